// Round 1
// baseline (3091.902 us; speedup 1.0000x reference)
//
#include <hip/hip_runtime.h>

#define NN 100000
#define NE 3200000
#define NG 128
#define HID 64
#define OUTC 128

// ---------------- degree count ----------------
__global__ void k_count(const int* __restrict__ dst, float* __restrict__ cnt) {
    int e = blockIdx.x * blockDim.x + threadIdx.x;
    if (e < NE) atomicAdd(&cnt[dst[e]], 1.0f);
}

// ---------------- layer-1 aggregation (d=3) ----------------
__global__ void k_agg3(const int* __restrict__ src, const int* __restrict__ dst,
                       const float* __restrict__ x, float* __restrict__ agg3) {
    int e = blockIdx.x * blockDim.x + threadIdx.x;
    if (e < NE) {
        int s = src[e], d = dst[e];
        atomicAdd(&agg3[d * 3 + 0], x[s * 3 + 0]);
        atomicAdd(&agg3[d * 3 + 1], x[s * 3 + 1]);
        atomicAdd(&agg3[d * 3 + 2], x[s * 3 + 2]);
    }
}

// ---------------- layer 1 transform: [N,3] -> relu([N,64]) ----------------
__global__ void k_layer1(const float* __restrict__ x, const float* __restrict__ agg3,
                         const float* __restrict__ cnt,
                         const float* __restrict__ Wl, const float* __restrict__ bl,
                         const float* __restrict__ Wr, float* __restrict__ out) {
    int tid = blockIdx.x * blockDim.x + threadIdx.x;
    int n = tid >> 6;
    int c = tid & 63;
    if (n >= NN) return;
    float ic = 1.0f / fmaxf(cnt[n], 1.0f);
    float acc = bl[c];
#pragma unroll
    for (int k = 0; k < 3; ++k) {
        acc += (agg3[n * 3 + k] * ic) * Wl[k * 64 + c] + x[n * 3 + k] * Wr[k * 64 + c];
    }
    out[n * 64 + c] = fmaxf(acc, 0.0f);
}

// ---------------- d=64 aggregation: one wave per edge ----------------
__global__ __launch_bounds__(256) void k_agg64(const int* __restrict__ src,
                                               const int* __restrict__ dst,
                                               const float* __restrict__ h,
                                               float* __restrict__ agg) {
    long long t = (long long)blockIdx.x * blockDim.x + threadIdx.x;
    int e = (int)(t >> 6);
    int lane = (int)(t & 63);
    if (e >= NE) return;
    int s = src[e], d = dst[e];
    atomicAdd(&agg[(long long)d * 64 + lane], h[(long long)s * 64 + lane]);
}

// ---------------- layers 2-4 transform: relu(mean@Wl + bl + h@Wr) ----------------
// out may alias agg (rows read into LDS before write; each block touches only its rows)
__global__ __launch_bounds__(256) void k_transform(
        const float* __restrict__ h, const float* __restrict__ agg,
        const float* __restrict__ cnt,
        const float* __restrict__ Wl, const float* __restrict__ bl,
        const float* __restrict__ Wr, float* __restrict__ out) {
    __shared__ float Ws[2][64 * 64];   // 32 KiB: Wl, Wr
    __shared__ float rows[2][4][64];   // mean rows, h rows for the 4 nodes
    for (int i = threadIdx.x; i < 64 * 64; i += 256) {
        Ws[0][i] = Wl[i];
        Ws[1][i] = Wr[i];
    }
    int li = threadIdx.x >> 6;
    int c = threadIdx.x & 63;
    int n = blockIdx.x * 4 + li;
    if (n < NN) {
        float ic = 1.0f / fmaxf(cnt[n], 1.0f);
        rows[0][li][c] = agg[n * 64 + c] * ic;
        rows[1][li][c] = h[n * 64 + c];
    }
    __syncthreads();
    if (n >= NN) return;
    float acc = bl[c];
#pragma unroll 8
    for (int k = 0; k < 64; ++k) {
        acc += rows[0][li][k] * Ws[0][k * 64 + c] + rows[1][li][k] * Ws[1][k * 64 + c];
    }
    out[n * 64 + c] = fmaxf(acc, 0.0f);
}

// ---------------- pooling helpers ----------------
__device__ __forceinline__ int lower_bound_batch(const int* __restrict__ batch, int val) {
    int lo = 0, hi = NN;
    while (lo < hi) {
        int mid = (lo + hi) >> 1;
        if (batch[mid] < val) lo = mid + 1; else hi = mid;
    }
    return lo;
}

// 8 blocks per graph, 64 threads (=cols); partial sums -> atomics (8 per addr)
__global__ __launch_bounds__(64) void k_pool(const float* __restrict__ h,
                                             const int* __restrict__ batch,
                                             float* __restrict__ psum) {
    int g = blockIdx.x >> 3;
    int part = blockIdx.x & 7;
    int lane = threadIdx.x;
    int lo = lower_bound_batch(batch, g);
    int hi = lower_bound_batch(batch, g + 1);
    float s = 0.0f;
    for (int n = lo + part; n < hi; n += 8) s += h[n * 64 + lane];
    atomicAdd(&psum[g * 64 + lane], s);
}

// ---------------- FC + row L2 normalize ----------------
__global__ __launch_bounds__(128) void k_fc(const float* __restrict__ psum,
                                            const int* __restrict__ batch,
                                            const float* __restrict__ Wfc,
                                            const float* __restrict__ bfc,
                                            float* __restrict__ out) {
    __shared__ float meanv[64];
    __shared__ float red[2];
    int g = blockIdx.x;
    int c = threadIdx.x;
    int lo = lower_bound_batch(batch, g);
    int hi = lower_bound_batch(batch, g + 1);
    float icnt = 1.0f / fmaxf((float)(hi - lo), 1.0f);
    if (c < 64) meanv[c] = psum[g * 64 + c] * icnt;
    __syncthreads();
    float acc = bfc[c];
#pragma unroll
    for (int k = 0; k < 64; ++k) acc += meanv[k] * Wfc[k * 128 + c];
    float ss = acc * acc;
#pragma unroll
    for (int off = 32; off; off >>= 1) ss += __shfl_down(ss, off);
    if ((c & 63) == 0) red[c >> 6] = ss;
    __syncthreads();
    float norm = fmaxf(sqrtf(red[0] + red[1]), 1e-12f);
    out[g * 128 + c] = acc / norm;
}

extern "C" void kernel_launch(void* const* d_in, const int* in_sizes, int n_in,
                              void* d_out, int out_size, void* d_ws, size_t ws_size,
                              hipStream_t stream) {
    const float* x    = (const float*)d_in[0];
    const int*   ei   = (const int*)d_in[1];
    const int*   src  = ei;
    const int*   dst  = ei + NE;
    const int*   batch = (const int*)d_in[2];
    const float* Wl1 = (const float*)d_in[3];
    const float* bl1 = (const float*)d_in[4];
    const float* Wr1 = (const float*)d_in[5];
    const float* Wl2 = (const float*)d_in[6];
    const float* bl2 = (const float*)d_in[7];
    const float* Wr2 = (const float*)d_in[8];
    const float* Wl3 = (const float*)d_in[9];
    const float* bl3 = (const float*)d_in[10];
    const float* Wr3 = (const float*)d_in[11];
    const float* Wl4 = (const float*)d_in[12];
    const float* bl4 = (const float*)d_in[13];
    const float* Wr4 = (const float*)d_in[14];
    const float* Wfc = (const float*)d_in[15];
    const float* bfc = (const float*)d_in[16];
    float* out = (float*)d_out;

    // workspace layout (floats)
    float* hA   = (float*)d_ws;                 // [N,64]
    float* hB   = hA + (size_t)NN * 64;         // [N,64]
    float* cnt  = hB + (size_t)NN * 64;         // [N]
    float* agg3 = cnt + NN;                     // [N,3]
    float* psum = agg3 + (size_t)NN * 3;        // [G,64]

    hipMemsetAsync(cnt, 0, NN * sizeof(float), stream);
    hipMemsetAsync(agg3, 0, (size_t)NN * 3 * sizeof(float), stream);
    hipMemsetAsync(psum, 0, (size_t)NG * 64 * sizeof(float), stream);

    k_count<<<(NE + 255) / 256, 256, 0, stream>>>(dst, cnt);
    k_agg3<<<(NE + 255) / 256, 256, 0, stream>>>(src, dst, x, agg3);
    k_layer1<<<(NN * 64 + 255) / 256, 256, 0, stream>>>(x, agg3, cnt, Wl1, bl1, Wr1, hA);

    const int aggGrid = NE / 4;            // (NE*64)/256
    const int trGrid  = (NN + 3) / 4;

    // layer 2: h=hA, agg->hB, out->hB
    hipMemsetAsync(hB, 0, (size_t)NN * 64 * sizeof(float), stream);
    k_agg64<<<aggGrid, 256, 0, stream>>>(src, dst, hA, hB);
    k_transform<<<trGrid, 256, 0, stream>>>(hA, hB, cnt, Wl2, bl2, Wr2, hB);

    // layer 3: h=hB, agg->hA, out->hA
    hipMemsetAsync(hA, 0, (size_t)NN * 64 * sizeof(float), stream);
    k_agg64<<<aggGrid, 256, 0, stream>>>(src, dst, hB, hA);
    k_transform<<<trGrid, 256, 0, stream>>>(hB, hA, cnt, Wl3, bl3, Wr3, hA);

    // layer 4: h=hA, agg->hB, out->hB
    hipMemsetAsync(hB, 0, (size_t)NN * 64 * sizeof(float), stream);
    k_agg64<<<aggGrid, 256, 0, stream>>>(src, dst, hA, hB);
    k_transform<<<trGrid, 256, 0, stream>>>(hA, hB, cnt, Wl4, bl4, Wr4, hB);

    k_pool<<<NG * 8, 64, 0, stream>>>(hB, batch, psum);
    k_fc<<<NG, 128, 0, stream>>>(psum, batch, Wfc, bfc, out);
}

// Round 2
// 1370.024 us; speedup vs baseline: 2.2568x; 2.2568x over previous
//
#include <hip/hip_runtime.h>

#define NN 100000
#define NE 3200000
#define NG 128
#define HID 64
#define OUTC 128

// ---------------- CSR build ----------------
__global__ void k_deg(const int* __restrict__ dst, int* __restrict__ deg) {
    int e = blockIdx.x * blockDim.x + threadIdx.x;
    if (e < NE) atomicAdd(&deg[dst[e]], 1);
}

// single-block exclusive scan over deg -> off[NN+1], cur[NN]
__global__ __launch_bounds__(1024) void k_scan(const int* __restrict__ deg,
                                               int* __restrict__ off,
                                               int* __restrict__ cur) {
    __shared__ int sums[1024];
    const int t = threadIdx.x;
    const int CH = (NN + 1023) / 1024;   // 98
    const int base = t * CH;
    int s = 0;
    for (int i = 0; i < CH; ++i) {
        int idx = base + i;
        if (idx < NN) s += deg[idx];
    }
    sums[t] = s;
    __syncthreads();
    for (int d = 1; d < 1024; d <<= 1) {
        int v = (t >= d) ? sums[t - d] : 0;
        __syncthreads();
        sums[t] += v;
        __syncthreads();
    }
    int run = (t == 0) ? 0 : sums[t - 1];
    for (int i = 0; i < CH; ++i) {
        int idx = base + i;
        if (idx < NN) {
            off[idx] = run;
            cur[idx] = run;
            run += deg[idx];
        }
    }
    if (t == 1023) off[NN] = sums[1023];
}

__global__ void k_scatter(const int* __restrict__ src, const int* __restrict__ dst,
                          int* __restrict__ cur, int* __restrict__ neigh) {
    int e = blockIdx.x * blockDim.x + threadIdx.x;
    if (e < NE) {
        int p = atomicAdd(&cur[dst[e]], 1);
        neigh[p] = src[e];
    }
}

// ---------------- layer 1: CSR mean-agg (d=3) + transform, fused ----------------
__global__ __launch_bounds__(256) void k_l1(const int* __restrict__ off,
                                            const int* __restrict__ neigh,
                                            const float* __restrict__ x,
                                            const float* __restrict__ Wl,
                                            const float* __restrict__ bl,
                                            const float* __restrict__ Wr,
                                            float* __restrict__ out) {
    int n = blockIdx.x * 4 + (threadIdx.x >> 6);
    int c = threadIdx.x & 63;
    if (n >= NN) return;
    int lo = off[n], hi = off[n + 1];
    float a0 = 0.f, a1 = 0.f, a2 = 0.f;
    for (int i = lo + c; i < hi; i += 64) {
        int s = neigh[i];
        a0 += x[s * 3 + 0];
        a1 += x[s * 3 + 1];
        a2 += x[s * 3 + 2];
    }
#pragma unroll
    for (int m = 1; m < 64; m <<= 1) {
        a0 += __shfl_xor(a0, m);
        a1 += __shfl_xor(a1, m);
        a2 += __shfl_xor(a2, m);
    }
    float ic = 1.0f / fmaxf((float)(hi - lo), 1.0f);
    a0 *= ic; a1 *= ic; a2 *= ic;
    float x0 = x[n * 3 + 0], x1 = x[n * 3 + 1], x2 = x[n * 3 + 2];
    float acc = bl[c]
              + a0 * Wl[0 * 64 + c] + a1 * Wl[1 * 64 + c] + a2 * Wl[2 * 64 + c]
              + x0 * Wr[0 * 64 + c] + x1 * Wr[1 * 64 + c] + x2 * Wr[2 * 64 + c];
    out[n * 64 + c] = fmaxf(acc, 0.0f);
}

// ---------------- d=64 CSR mean aggregation: one wave per node ----------------
__global__ __launch_bounds__(256) void k_aggm(const int* __restrict__ off,
                                              const int* __restrict__ neigh,
                                              const float* __restrict__ h,
                                              float* __restrict__ mean) {
    int n = blockIdx.x * 4 + (threadIdx.x >> 6);
    int lane = threadIdx.x & 63;
    if (n >= NN) return;
    int lo = off[n], hi = off[n + 1];
    float acc = 0.f;
    int i = lo;
    for (; i + 4 <= hi; i += 4) {
        int s0 = neigh[i + 0], s1 = neigh[i + 1], s2 = neigh[i + 2], s3 = neigh[i + 3];
        float v0 = h[(size_t)s0 * 64 + lane];
        float v1 = h[(size_t)s1 * 64 + lane];
        float v2 = h[(size_t)s2 * 64 + lane];
        float v3 = h[(size_t)s3 * 64 + lane];
        acc += v0 + v1 + v2 + v3;
    }
    for (; i < hi; ++i) {
        int s = neigh[i];
        acc += h[(size_t)s * 64 + lane];
    }
    mean[n * 64 + lane] = acc / fmaxf((float)(hi - lo), 1.0f);
}

// ---------------- layers 2-4 transform: relu(mean@Wl + bl + h@Wr) ----------------
// out may alias mean (rows read into LDS before write; each block touches only its rows)
__global__ __launch_bounds__(256) void k_transform(
        const float* __restrict__ h, const float* __restrict__ mean,
        const float* __restrict__ Wl, const float* __restrict__ bl,
        const float* __restrict__ Wr, float* __restrict__ out) {
    __shared__ float Ws[2][64 * 64];   // 32 KiB: Wl, Wr
    __shared__ float rows[2][4][64];   // mean rows, h rows for the 4 nodes
    for (int i = threadIdx.x; i < 64 * 64; i += 256) {
        Ws[0][i] = Wl[i];
        Ws[1][i] = Wr[i];
    }
    int li = threadIdx.x >> 6;
    int c = threadIdx.x & 63;
    int n = blockIdx.x * 4 + li;
    if (n < NN) {
        rows[0][li][c] = mean[n * 64 + c];
        rows[1][li][c] = h[n * 64 + c];
    }
    __syncthreads();
    if (n >= NN) return;
    float acc = bl[c];
#pragma unroll 8
    for (int k = 0; k < 64; ++k) {
        acc += rows[0][li][k] * Ws[0][k * 64 + c] + rows[1][li][k] * Ws[1][k * 64 + c];
    }
    out[n * 64 + c] = fmaxf(acc, 0.0f);
}

// ---------------- pooling helpers ----------------
__device__ __forceinline__ int lower_bound_batch(const int* __restrict__ batch, int val) {
    int lo = 0, hi = NN;
    while (lo < hi) {
        int mid = (lo + hi) >> 1;
        if (batch[mid] < val) lo = mid + 1; else hi = mid;
    }
    return lo;
}

// 8 blocks per graph, 64 threads (=cols); partial sums -> atomics (8 per addr)
__global__ __launch_bounds__(64) void k_pool(const float* __restrict__ h,
                                             const int* __restrict__ batch,
                                             float* __restrict__ psum) {
    int g = blockIdx.x >> 3;
    int part = blockIdx.x & 7;
    int lane = threadIdx.x;
    int lo = lower_bound_batch(batch, g);
    int hi = lower_bound_batch(batch, g + 1);
    float s = 0.0f;
    for (int n = lo + part; n < hi; n += 8) s += h[n * 64 + lane];
    atomicAdd(&psum[g * 64 + lane], s);
}

// ---------------- FC + row L2 normalize ----------------
__global__ __launch_bounds__(128) void k_fc(const float* __restrict__ psum,
                                            const int* __restrict__ batch,
                                            const float* __restrict__ Wfc,
                                            const float* __restrict__ bfc,
                                            float* __restrict__ out) {
    __shared__ float meanv[64];
    __shared__ float red[2];
    int g = blockIdx.x;
    int c = threadIdx.x;
    int lo = lower_bound_batch(batch, g);
    int hi = lower_bound_batch(batch, g + 1);
    float icnt = 1.0f / fmaxf((float)(hi - lo), 1.0f);
    if (c < 64) meanv[c] = psum[g * 64 + c] * icnt;
    __syncthreads();
    float acc = bfc[c];
#pragma unroll
    for (int k = 0; k < 64; ++k) acc += meanv[k] * Wfc[k * 128 + c];
    float ss = acc * acc;
#pragma unroll
    for (int off = 32; off; off >>= 1) ss += __shfl_down(ss, off);
    if ((c & 63) == 0) red[c >> 6] = ss;
    __syncthreads();
    float norm = fmaxf(sqrtf(red[0] + red[1]), 1e-12f);
    out[g * 128 + c] = acc / norm;
}

extern "C" void kernel_launch(void* const* d_in, const int* in_sizes, int n_in,
                              void* d_out, int out_size, void* d_ws, size_t ws_size,
                              hipStream_t stream) {
    const float* x    = (const float*)d_in[0];
    const int*   ei   = (const int*)d_in[1];
    const int*   src  = ei;
    const int*   dst  = ei + NE;
    const int*   batch = (const int*)d_in[2];
    const float* Wl1 = (const float*)d_in[3];
    const float* bl1 = (const float*)d_in[4];
    const float* Wr1 = (const float*)d_in[5];
    const float* Wl2 = (const float*)d_in[6];
    const float* bl2 = (const float*)d_in[7];
    const float* Wr2 = (const float*)d_in[8];
    const float* Wl3 = (const float*)d_in[9];
    const float* bl3 = (const float*)d_in[10];
    const float* Wr3 = (const float*)d_in[11];
    const float* Wl4 = (const float*)d_in[12];
    const float* bl4 = (const float*)d_in[13];
    const float* Wr4 = (const float*)d_in[14];
    const float* Wfc = (const float*)d_in[15];
    const float* bfc = (const float*)d_in[16];
    float* out = (float*)d_out;

    // workspace layout
    float* hA   = (float*)d_ws;                 // [N,64]
    float* hB   = hA + (size_t)NN * 64;         // [N,64]
    float* psum = hB + (size_t)NN * 64;         // [G,64]
    int*   deg  = (int*)(psum + (size_t)NG * 64);  // [N]
    int*   off  = deg + NN;                     // [N+1]
    int*   cur  = off + NN + 1;                 // [N]
    int*   neigh = cur + NN;                    // [E]

    hipMemsetAsync(deg, 0, NN * sizeof(int), stream);
    hipMemsetAsync(psum, 0, (size_t)NG * 64 * sizeof(float), stream);

    // CSR build (dst-sorted adjacency)
    k_deg<<<(NE + 255) / 256, 256, 0, stream>>>(dst, deg);
    k_scan<<<1, 1024, 0, stream>>>(deg, off, cur);
    k_scatter<<<(NE + 255) / 256, 256, 0, stream>>>(src, dst, cur, neigh);

    const int nodeGrid = (NN + 3) / 4;

    // layer 1 (fused d=3 agg + transform)
    k_l1<<<nodeGrid, 256, 0, stream>>>(off, neigh, x, Wl1, bl1, Wr1, hA);

    // layer 2: agg(hA)->hB, transform(hA,hB)->hB
    k_aggm<<<nodeGrid, 256, 0, stream>>>(off, neigh, hA, hB);
    k_transform<<<nodeGrid, 256, 0, stream>>>(hA, hB, Wl2, bl2, Wr2, hB);

    // layer 3: agg(hB)->hA, transform(hB,hA)->hA
    k_aggm<<<nodeGrid, 256, 0, stream>>>(off, neigh, hB, hA);
    k_transform<<<nodeGrid, 256, 0, stream>>>(hB, hA, Wl3, bl3, Wr3, hA);

    // layer 4: agg(hA)->hB, transform(hA,hB)->hB
    k_aggm<<<nodeGrid, 256, 0, stream>>>(off, neigh, hA, hB);
    k_transform<<<nodeGrid, 256, 0, stream>>>(hA, hB, Wl4, bl4, Wr4, hB);

    k_pool<<<NG * 8, 64, 0, stream>>>(hB, batch, psum);
    k_fc<<<NG, 128, 0, stream>>>(psum, batch, Wfc, bfc, out);
}

// Round 3
// 1339.219 us; speedup vs baseline: 2.3087x; 1.0230x over previous
//
#include <hip/hip_runtime.h>

#define NN 100000
#define NE 3200000
#define NG 128
#define HID 64
#define OUTC 128

// ---------------- adjacency build: linked list (coalesced writes) ----------------
__global__ void k_build(const int* __restrict__ dst, int* __restrict__ head,
                        int* __restrict__ next, int* __restrict__ deg) {
    int e = blockIdx.x * blockDim.x + threadIdx.x;
    if (e < NE) {
        int d = dst[e];
        next[e] = atomicExch(&head[d], e);   // next write coalesced by e
        atomicAdd(&deg[d], 1);
    }
}

// single-block exclusive scan over deg -> off[NN+1]
__global__ __launch_bounds__(1024) void k_scan(const int* __restrict__ deg,
                                               int* __restrict__ off) {
    __shared__ int sums[1024];
    const int t = threadIdx.x;
    const int CH = (NN + 1023) / 1024;   // 98
    const int base = t * CH;
    int s = 0;
    for (int i = 0; i < CH; ++i) {
        int idx = base + i;
        if (idx < NN) s += deg[idx];
    }
    sums[t] = s;
    __syncthreads();
    for (int d = 1; d < 1024; d <<= 1) {
        int v = (t >= d) ? sums[t - d] : 0;
        __syncthreads();
        sums[t] += v;
        __syncthreads();
    }
    int run = (t == 0) ? 0 : sums[t - 1];
    for (int i = 0; i < CH; ++i) {
        int idx = base + i;
        if (idx < NN) {
            off[idx] = run;
            run += deg[idx];
        }
    }
    if (t == 1023) off[NN] = sums[1023];
}

// list -> CSR: one lane per node, sequential per-node writes (full-line fills)
__global__ __launch_bounds__(256) void k_l2c(const int* __restrict__ head,
                                             const int* __restrict__ next,
                                             const int* __restrict__ src,
                                             const int* __restrict__ off,
                                             int* __restrict__ neigh) {
    int n = blockIdx.x * blockDim.x + threadIdx.x;
    if (n >= NN) return;
    int p = off[n];
    int e = head[n];
    while (e >= 0) {
        int nx = next[e];
        int s = src[e];
        neigh[p++] = s;
        e = nx;
    }
}

// ---------------- layer 1: CSR mean-agg (d=3) + transform, fused ----------------
__global__ __launch_bounds__(256) void k_l1(const int* __restrict__ off,
                                            const int* __restrict__ neigh,
                                            const float* __restrict__ x,
                                            const float* __restrict__ Wl,
                                            const float* __restrict__ bl,
                                            const float* __restrict__ Wr,
                                            float* __restrict__ out) {
    int n = blockIdx.x * 4 + (threadIdx.x >> 6);
    int c = threadIdx.x & 63;
    if (n >= NN) return;
    int lo = off[n], hi = off[n + 1];
    float a0 = 0.f, a1 = 0.f, a2 = 0.f;
    for (int i = lo + c; i < hi; i += 64) {
        int s = neigh[i];
        a0 += x[s * 3 + 0];
        a1 += x[s * 3 + 1];
        a2 += x[s * 3 + 2];
    }
#pragma unroll
    for (int m = 1; m < 64; m <<= 1) {
        a0 += __shfl_xor(a0, m);
        a1 += __shfl_xor(a1, m);
        a2 += __shfl_xor(a2, m);
    }
    float ic = 1.0f / fmaxf((float)(hi - lo), 1.0f);
    a0 *= ic; a1 *= ic; a2 *= ic;
    float x0 = x[n * 3 + 0], x1 = x[n * 3 + 1], x2 = x[n * 3 + 2];
    float acc = bl[c]
              + a0 * Wl[0 * 64 + c] + a1 * Wl[1 * 64 + c] + a2 * Wl[2 * 64 + c]
              + x0 * Wr[0 * 64 + c] + x1 * Wr[1 * 64 + c] + x2 * Wr[2 * 64 + c];
    out[n * 64 + c] = fmaxf(acc, 0.0f);
}

// ---------------- d=64 CSR mean aggregation: one wave per node ----------------
__global__ __launch_bounds__(256) void k_aggm(const int* __restrict__ off,
                                              const int* __restrict__ neigh,
                                              const float* __restrict__ h,
                                              float* __restrict__ mean) {
    int n = blockIdx.x * 4 + (threadIdx.x >> 6);
    int lane = threadIdx.x & 63;
    if (n >= NN) return;
    int lo = off[n], hi = off[n + 1];
    float acc = 0.f;
    int i = lo;
    for (; i + 4 <= hi; i += 4) {
        int s0 = neigh[i + 0], s1 = neigh[i + 1], s2 = neigh[i + 2], s3 = neigh[i + 3];
        float v0 = h[(size_t)s0 * 64 + lane];
        float v1 = h[(size_t)s1 * 64 + lane];
        float v2 = h[(size_t)s2 * 64 + lane];
        float v3 = h[(size_t)s3 * 64 + lane];
        acc += v0 + v1 + v2 + v3;
    }
    for (; i < hi; ++i) {
        int s = neigh[i];
        acc += h[(size_t)s * 64 + lane];
    }
    mean[n * 64 + lane] = acc / fmaxf((float)(hi - lo), 1.0f);
}

// ---------------- layers 2-4 transform: relu(mean@Wl + bl + h@Wr) ----------------
// out may alias mean (rows read into LDS before write; each block touches only its rows)
__global__ __launch_bounds__(256) void k_transform(
        const float* __restrict__ h, const float* __restrict__ mean,
        const float* __restrict__ Wl, const float* __restrict__ bl,
        const float* __restrict__ Wr, float* __restrict__ out) {
    __shared__ float Ws[2][64 * 64];   // 32 KiB: Wl, Wr
    __shared__ float rows[2][4][64];   // mean rows, h rows for the 4 nodes
    for (int i = threadIdx.x; i < 64 * 64; i += 256) {
        Ws[0][i] = Wl[i];
        Ws[1][i] = Wr[i];
    }
    int li = threadIdx.x >> 6;
    int c = threadIdx.x & 63;
    int n = blockIdx.x * 4 + li;
    if (n < NN) {
        rows[0][li][c] = mean[n * 64 + c];
        rows[1][li][c] = h[n * 64 + c];
    }
    __syncthreads();
    if (n >= NN) return;
    float acc = bl[c];
#pragma unroll 8
    for (int k = 0; k < 64; ++k) {
        acc += rows[0][li][k] * Ws[0][k * 64 + c] + rows[1][li][k] * Ws[1][k * 64 + c];
    }
    out[n * 64 + c] = fmaxf(acc, 0.0f);
}

// ---------------- pooling helpers ----------------
__device__ __forceinline__ int lower_bound_batch(const int* __restrict__ batch, int val) {
    int lo = 0, hi = NN;
    while (lo < hi) {
        int mid = (lo + hi) >> 1;
        if (batch[mid] < val) lo = mid + 1; else hi = mid;
    }
    return lo;
}

// 8 blocks per graph, 64 threads (=cols); partial sums -> atomics (8 per addr)
__global__ __launch_bounds__(64) void k_pool(const float* __restrict__ h,
                                             const int* __restrict__ batch,
                                             float* __restrict__ psum) {
    int g = blockIdx.x >> 3;
    int part = blockIdx.x & 7;
    int lane = threadIdx.x;
    int lo = lower_bound_batch(batch, g);
    int hi = lower_bound_batch(batch, g + 1);
    float s = 0.0f;
    for (int n = lo + part; n < hi; n += 8) s += h[n * 64 + lane];
    atomicAdd(&psum[g * 64 + lane], s);
}

// ---------------- FC + row L2 normalize ----------------
__global__ __launch_bounds__(128) void k_fc(const float* __restrict__ psum,
                                            const int* __restrict__ batch,
                                            const float* __restrict__ Wfc,
                                            const float* __restrict__ bfc,
                                            float* __restrict__ out) {
    __shared__ float meanv[64];
    __shared__ float red[2];
    int g = blockIdx.x;
    int c = threadIdx.x;
    int lo = lower_bound_batch(batch, g);
    int hi = lower_bound_batch(batch, g + 1);
    float icnt = 1.0f / fmaxf((float)(hi - lo), 1.0f);
    if (c < 64) meanv[c] = psum[g * 64 + c] * icnt;
    __syncthreads();
    float acc = bfc[c];
#pragma unroll
    for (int k = 0; k < 64; ++k) acc += meanv[k] * Wfc[k * 128 + c];
    float ss = acc * acc;
#pragma unroll
    for (int off = 32; off; off >>= 1) ss += __shfl_down(ss, off);
    if ((c & 63) == 0) red[c >> 6] = ss;
    __syncthreads();
    float norm = fmaxf(sqrtf(red[0] + red[1]), 1e-12f);
    out[g * 128 + c] = acc / norm;
}

extern "C" void kernel_launch(void* const* d_in, const int* in_sizes, int n_in,
                              void* d_out, int out_size, void* d_ws, size_t ws_size,
                              hipStream_t stream) {
    const float* x    = (const float*)d_in[0];
    const int*   ei   = (const int*)d_in[1];
    const int*   src  = ei;
    const int*   dst  = ei + NE;
    const int*   batch = (const int*)d_in[2];
    const float* Wl1 = (const float*)d_in[3];
    const float* bl1 = (const float*)d_in[4];
    const float* Wr1 = (const float*)d_in[5];
    const float* Wl2 = (const float*)d_in[6];
    const float* bl2 = (const float*)d_in[7];
    const float* Wr2 = (const float*)d_in[8];
    const float* Wl3 = (const float*)d_in[9];
    const float* bl3 = (const float*)d_in[10];
    const float* Wr3 = (const float*)d_in[11];
    const float* Wl4 = (const float*)d_in[12];
    const float* bl4 = (const float*)d_in[13];
    const float* Wr4 = (const float*)d_in[14];
    const float* Wfc = (const float*)d_in[15];
    const float* bfc = (const float*)d_in[16];
    float* out = (float*)d_out;

    // workspace layout
    float* hA   = (float*)d_ws;                    // [N,64]
    float* hB   = hA + (size_t)NN * 64;            // [N,64]
    float* psum = hB + (size_t)NN * 64;            // [G,64]
    int*   deg  = (int*)(psum + (size_t)NG * 64);  // [N]
    int*   off  = deg + NN;                        // [N+1]
    int*   head = off + NN + 1;                    // [N]
    int*   next = head + NN;                       // [E]
    int*   neigh = next + NE;                      // [E]

    hipMemsetAsync(deg, 0, NN * sizeof(int), stream);
    hipMemsetAsync(head, 0xFF, NN * sizeof(int), stream);   // -1
    hipMemsetAsync(psum, 0, (size_t)NG * 64 * sizeof(float), stream);

    // adjacency build: linked list + deg (one pass over dst), scan, list->CSR
    k_build<<<(NE + 255) / 256, 256, 0, stream>>>(dst, head, next, deg);
    k_scan<<<1, 1024, 0, stream>>>(deg, off);
    k_l2c<<<(NN + 255) / 256, 256, 0, stream>>>(head, next, src, off, neigh);

    const int nodeGrid = (NN + 3) / 4;

    // layer 1 (fused d=3 agg + transform)
    k_l1<<<nodeGrid, 256, 0, stream>>>(off, neigh, x, Wl1, bl1, Wr1, hA);

    // layer 2: agg(hA)->hB, transform(hA,hB)->hB
    k_aggm<<<nodeGrid, 256, 0, stream>>>(off, neigh, hA, hB);
    k_transform<<<nodeGrid, 256, 0, stream>>>(hA, hB, Wl2, bl2, Wr2, hB);

    // layer 3: agg(hB)->hA, transform(hB,hA)->hA
    k_aggm<<<nodeGrid, 256, 0, stream>>>(off, neigh, hB, hA);
    k_transform<<<nodeGrid, 256, 0, stream>>>(hB, hA, Wl3, bl3, Wr3, hA);

    // layer 4: agg(hA)->hB, transform(hA,hB)->hB
    k_aggm<<<nodeGrid, 256, 0, stream>>>(off, neigh, hA, hB);
    k_transform<<<nodeGrid, 256, 0, stream>>>(hA, hB, Wl4, bl4, Wr4, hB);

    k_pool<<<NG * 8, 64, 0, stream>>>(hB, batch, psum);
    k_fc<<<NG, 128, 0, stream>>>(psum, batch, Wfc, bfc, out);
}

// Round 4
// 863.239 us; speedup vs baseline: 3.5817x; 1.5514x over previous
//
#include <hip/hip_runtime.h>

#define NN 100000
#define NE 3200000
#define NG 128
#define HID 64
#define OUTC 128

#define CHUNK 8192
#define NBLK 391                 // ceil(NE / CHUNK)
#define NB1 782                  // ceil(NN / 128) coarse buckets (dst >> 7)

// ---------------- P1: per-block coarse histogram (LDS atomics only) ----------------
__global__ __launch_bounds__(256) void k_hist(const int* __restrict__ dst,
                                              int* __restrict__ hist1) {
    __shared__ int h[NB1];
    for (int i = threadIdx.x; i < NB1; i += 256) h[i] = 0;
    __syncthreads();
    int base = blockIdx.x * CHUNK;
    int end = min(base + CHUNK, NE);
    for (int e = base + threadIdx.x; e < end; e += 256)
        atomicAdd(&h[dst[e] >> 7], 1);
    __syncthreads();
    for (int i = threadIdx.x; i < NB1; i += 256)
        hist1[i * NBLK + blockIdx.x] = h[i];
}

// ---------------- P2: transpose-scan hist1 -> per-(bucket,block) bases + bb ----------------
__global__ __launch_bounds__(1024) void k_scanbk(int* __restrict__ hist1,
                                                 int* __restrict__ bb) {
    __shared__ int tot_s[1024];
    int t = threadIdx.x;
    int tot = 0;
    if (t < NB1) {
        for (int k = 0; k < NBLK; ++k) tot += hist1[t * NBLK + k];
    }
    tot_s[t] = tot;
    __syncthreads();
    for (int d = 1; d < 1024; d <<= 1) {
        int v = (t >= d) ? tot_s[t - d] : 0;
        __syncthreads();
        tot_s[t] += v;
        __syncthreads();
    }
    int base = (t == 0) ? 0 : tot_s[t - 1];
    if (t < NB1) {
        bb[t] = base;
        int run = base;
        for (int k = 0; k < NBLK; ++k) {
            int v = hist1[t * NBLK + k];
            hist1[t * NBLK + k] = run;
            run += v;
        }
    }
    if (t == 0) bb[NB1] = NE;
}

// ---------------- P3: scatter into coarse buckets (LDS cursors, no device atomics) ----------------
__global__ __launch_bounds__(256) void k_scat(const int* __restrict__ src,
                                              const int* __restrict__ dst,
                                              const int* __restrict__ hist1,
                                              int* __restrict__ packed) {
    __shared__ int cur[NB1];
    for (int i = threadIdx.x; i < NB1; i += 256)
        cur[i] = hist1[i * NBLK + blockIdx.x];
    __syncthreads();
    int base = blockIdx.x * CHUNK;
    int end = min(base + CHUNK, NE);
    for (int e = base + threadIdx.x; e < end; e += 256) {
        int d = dst[e], s = src[e];
        int p = atomicAdd(&cur[d >> 7], 1);
        packed[p] = ((d & 127) << 17) | s;   // src < 2^17
    }
}

// ---------------- P4: within-bucket group by exact dst; emit neigh + off ----------------
__global__ __launch_bounds__(256) void k_bucket(const int* __restrict__ packed,
                                                const int* __restrict__ bb,
                                                int* __restrict__ neigh,
                                                int* __restrict__ off) {
    int b = blockIdx.x;
    int lo = bb[b], hi = bb[b + 1];
    __shared__ int cnt[128];
    __shared__ int pos[128];
    __shared__ int cur2[128];
    if (threadIdx.x < 128) cnt[threadIdx.x] = 0;
    __syncthreads();
    for (int i = lo + threadIdx.x; i < hi; i += 256)
        atomicAdd(&cnt[packed[i] >> 17], 1);
    __syncthreads();
    if (threadIdx.x == 0) {
        int run = lo;
        for (int j = 0; j < 128; ++j) { pos[j] = run; run += cnt[j]; }
    }
    __syncthreads();
    if (threadIdx.x < 128) {
        int node = b * 128 + threadIdx.x;
        if (node <= NN) off[node] = pos[threadIdx.x];
        cur2[threadIdx.x] = pos[threadIdx.x];
    }
    __syncthreads();
    for (int i = lo + threadIdx.x; i < hi; i += 256) {
        int p = packed[i];
        int j = p >> 17;
        int q = atomicAdd(&cur2[j], 1);
        neigh[q] = p & 0x1FFFF;
    }
}

// ---------------- layer 1: CSR mean-agg (d=3) + transform, fused ----------------
__global__ __launch_bounds__(256) void k_l1(const int* __restrict__ off,
                                            const int* __restrict__ neigh,
                                            const float* __restrict__ x,
                                            const float* __restrict__ Wl,
                                            const float* __restrict__ bl,
                                            const float* __restrict__ Wr,
                                            float* __restrict__ out) {
    int n = blockIdx.x * 4 + (threadIdx.x >> 6);
    int c = threadIdx.x & 63;
    if (n >= NN) return;
    int lo = off[n], hi = off[n + 1];
    float a0 = 0.f, a1 = 0.f, a2 = 0.f;
    for (int i = lo + c; i < hi; i += 64) {
        int s = neigh[i];
        a0 += x[s * 3 + 0];
        a1 += x[s * 3 + 1];
        a2 += x[s * 3 + 2];
    }
#pragma unroll
    for (int m = 1; m < 64; m <<= 1) {
        a0 += __shfl_xor(a0, m);
        a1 += __shfl_xor(a1, m);
        a2 += __shfl_xor(a2, m);
    }
    float ic = 1.0f / fmaxf((float)(hi - lo), 1.0f);
    a0 *= ic; a1 *= ic; a2 *= ic;
    float x0 = x[n * 3 + 0], x1 = x[n * 3 + 1], x2 = x[n * 3 + 2];
    float acc = bl[c]
              + a0 * Wl[0 * 64 + c] + a1 * Wl[1 * 64 + c] + a2 * Wl[2 * 64 + c]
              + x0 * Wr[0 * 64 + c] + x1 * Wr[1 * 64 + c] + x2 * Wr[2 * 64 + c];
    out[n * 64 + c] = fmaxf(acc, 0.0f);
}

// ---------------- d=64 CSR mean aggregation: one wave per node, unroll 8 ----------------
__global__ __launch_bounds__(256) void k_aggm(const int* __restrict__ off,
                                              const int* __restrict__ neigh,
                                              const float* __restrict__ h,
                                              float* __restrict__ mean) {
    int n = blockIdx.x * 4 + (threadIdx.x >> 6);
    int lane = threadIdx.x & 63;
    if (n >= NN) return;
    int lo = off[n], hi = off[n + 1];
    float acc = 0.f;
    int i = lo;
    for (; i + 8 <= hi; i += 8) {
        int s0 = neigh[i + 0], s1 = neigh[i + 1], s2 = neigh[i + 2], s3 = neigh[i + 3];
        int s4 = neigh[i + 4], s5 = neigh[i + 5], s6 = neigh[i + 6], s7 = neigh[i + 7];
        float v0 = h[(size_t)s0 * 64 + lane];
        float v1 = h[(size_t)s1 * 64 + lane];
        float v2 = h[(size_t)s2 * 64 + lane];
        float v3 = h[(size_t)s3 * 64 + lane];
        float v4 = h[(size_t)s4 * 64 + lane];
        float v5 = h[(size_t)s5 * 64 + lane];
        float v6 = h[(size_t)s6 * 64 + lane];
        float v7 = h[(size_t)s7 * 64 + lane];
        acc += ((v0 + v1) + (v2 + v3)) + ((v4 + v5) + (v6 + v7));
    }
    for (; i < hi; ++i) {
        int s = neigh[i];
        acc += h[(size_t)s * 64 + lane];
    }
    mean[n * 64 + lane] = acc / fmaxf((float)(hi - lo), 1.0f);
}

// ---------------- layers 2-4 transform: relu(mean@Wl + bl + h@Wr) ----------------
__global__ __launch_bounds__(256) void k_transform(
        const float* __restrict__ h, const float* __restrict__ mean,
        const float* __restrict__ Wl, const float* __restrict__ bl,
        const float* __restrict__ Wr, float* __restrict__ out) {
    __shared__ float Ws[2][64 * 64];   // 32 KiB: Wl, Wr
    __shared__ float rows[2][4][64];   // mean rows, h rows for the 4 nodes
    for (int i = threadIdx.x; i < 64 * 64; i += 256) {
        Ws[0][i] = Wl[i];
        Ws[1][i] = Wr[i];
    }
    int li = threadIdx.x >> 6;
    int c = threadIdx.x & 63;
    int n = blockIdx.x * 4 + li;
    if (n < NN) {
        rows[0][li][c] = mean[n * 64 + c];
        rows[1][li][c] = h[n * 64 + c];
    }
    __syncthreads();
    if (n >= NN) return;
    float acc = bl[c];
#pragma unroll 8
    for (int k = 0; k < 64; ++k) {
        acc += rows[0][li][k] * Ws[0][k * 64 + c] + rows[1][li][k] * Ws[1][k * 64 + c];
    }
    out[n * 64 + c] = fmaxf(acc, 0.0f);
}

// ---------------- pooling helpers ----------------
__device__ __forceinline__ int lower_bound_batch(const int* __restrict__ batch, int val) {
    int lo = 0, hi = NN;
    while (lo < hi) {
        int mid = (lo + hi) >> 1;
        if (batch[mid] < val) lo = mid + 1; else hi = mid;
    }
    return lo;
}

__global__ __launch_bounds__(64) void k_pool(const float* __restrict__ h,
                                             const int* __restrict__ batch,
                                             float* __restrict__ psum) {
    int g = blockIdx.x >> 3;
    int part = blockIdx.x & 7;
    int lane = threadIdx.x;
    int lo = lower_bound_batch(batch, g);
    int hi = lower_bound_batch(batch, g + 1);
    float s = 0.0f;
    for (int n = lo + part; n < hi; n += 8) s += h[n * 64 + lane];
    atomicAdd(&psum[g * 64 + lane], s);
}

__global__ __launch_bounds__(128) void k_fc(const float* __restrict__ psum,
                                            const int* __restrict__ batch,
                                            const float* __restrict__ Wfc,
                                            const float* __restrict__ bfc,
                                            float* __restrict__ out) {
    __shared__ float meanv[64];
    __shared__ float red[2];
    int g = blockIdx.x;
    int c = threadIdx.x;
    int lo = lower_bound_batch(batch, g);
    int hi = lower_bound_batch(batch, g + 1);
    float icnt = 1.0f / fmaxf((float)(hi - lo), 1.0f);
    if (c < 64) meanv[c] = psum[g * 64 + c] * icnt;
    __syncthreads();
    float acc = bfc[c];
#pragma unroll
    for (int k = 0; k < 64; ++k) acc += meanv[k] * Wfc[k * 128 + c];
    float ss = acc * acc;
#pragma unroll
    for (int off = 32; off; off >>= 1) ss += __shfl_down(ss, off);
    if ((c & 63) == 0) red[c >> 6] = ss;
    __syncthreads();
    float norm = fmaxf(sqrtf(red[0] + red[1]), 1e-12f);
    out[g * 128 + c] = acc / norm;
}

extern "C" void kernel_launch(void* const* d_in, const int* in_sizes, int n_in,
                              void* d_out, int out_size, void* d_ws, size_t ws_size,
                              hipStream_t stream) {
    const float* x    = (const float*)d_in[0];
    const int*   ei   = (const int*)d_in[1];
    const int*   src  = ei;
    const int*   dst  = ei + NE;
    const int*   batch = (const int*)d_in[2];
    const float* Wl1 = (const float*)d_in[3];
    const float* bl1 = (const float*)d_in[4];
    const float* Wr1 = (const float*)d_in[5];
    const float* Wl2 = (const float*)d_in[6];
    const float* bl2 = (const float*)d_in[7];
    const float* Wr2 = (const float*)d_in[8];
    const float* Wl3 = (const float*)d_in[9];
    const float* bl3 = (const float*)d_in[10];
    const float* Wr3 = (const float*)d_in[11];
    const float* Wl4 = (const float*)d_in[12];
    const float* bl4 = (const float*)d_in[13];
    const float* Wr4 = (const float*)d_in[14];
    const float* Wfc = (const float*)d_in[15];
    const float* bfc = (const float*)d_in[16];
    float* out = (float*)d_out;

    // workspace layout
    float* hA    = (float*)d_ws;                     // [N,64]
    float* hB    = hA + (size_t)NN * 64;             // [N,64]
    float* psum  = hB + (size_t)NN * 64;             // [G,64]
    int*   off   = (int*)(psum + (size_t)NG * 64);   // [N+1]
    int*   bb    = off + NN + 1;                     // [NB1+1]
    int*   hist1 = bb + NB1 + 1;                     // [NB1*NBLK]
    int*   packed = hist1 + NB1 * NBLK;              // [E]
    int*   neigh  = packed + NE;                     // [E]

    hipMemsetAsync(psum, 0, (size_t)NG * 64 * sizeof(float), stream);

    // CSR build: atomic-free (LDS-privatized two-level bucket sort)
    k_hist<<<NBLK, 256, 0, stream>>>(dst, hist1);
    k_scanbk<<<1, 1024, 0, stream>>>(hist1, bb);
    k_scat<<<NBLK, 256, 0, stream>>>(src, dst, hist1, packed);
    k_bucket<<<NB1, 256, 0, stream>>>(packed, bb, neigh, off);

    const int nodeGrid = (NN + 3) / 4;

    // layer 1 (fused d=3 agg + transform)
    k_l1<<<nodeGrid, 256, 0, stream>>>(off, neigh, x, Wl1, bl1, Wr1, hA);

    // layer 2: agg(hA)->hB, transform(hA,hB)->hB
    k_aggm<<<nodeGrid, 256, 0, stream>>>(off, neigh, hA, hB);
    k_transform<<<nodeGrid, 256, 0, stream>>>(hA, hB, Wl2, bl2, Wr2, hB);

    // layer 3: agg(hB)->hA, transform(hB,hA)->hA
    k_aggm<<<nodeGrid, 256, 0, stream>>>(off, neigh, hB, hA);
    k_transform<<<nodeGrid, 256, 0, stream>>>(hB, hA, Wl3, bl3, Wr3, hA);

    // layer 4: agg(hA)->hB, transform(hA,hB)->hB
    k_aggm<<<nodeGrid, 256, 0, stream>>>(off, neigh, hA, hB);
    k_transform<<<nodeGrid, 256, 0, stream>>>(hA, hB, Wl4, bl4, Wr4, hB);

    k_pool<<<NG * 8, 64, 0, stream>>>(hB, batch, psum);
    k_fc<<<NG, 128, 0, stream>>>(psum, batch, Wfc, bfc, out);
}

// Round 5
// 846.306 us; speedup vs baseline: 3.6534x; 1.0200x over previous
//
#include <hip/hip_runtime.h>

#define NN 100000
#define NE 3200000
#define NG 128
#define HID 64
#define OUTC 128

#define CHUNK 8192
#define NBLK 391                 // ceil(NE / CHUNK)
#define NB1 782                  // ceil(NN / 128) coarse buckets (dst >> 7)

// ---------------- P1: per-block coarse histogram (LDS atomics only) ----------------
__global__ __launch_bounds__(256) void k_hist(const int* __restrict__ dst,
                                              int* __restrict__ hist1) {
    __shared__ int h[NB1];
    for (int i = threadIdx.x; i < NB1; i += 256) h[i] = 0;
    __syncthreads();
    int base = blockIdx.x * CHUNK;
    int end = min(base + CHUNK, NE);
    for (int e = base + threadIdx.x; e < end; e += 256)
        atomicAdd(&h[dst[e] >> 7], 1);
    __syncthreads();
    for (int i = threadIdx.x; i < NB1; i += 256)
        hist1[i * NBLK + blockIdx.x] = h[i];
}

// ---------------- P2a: per-row totals (one wave per row) ----------------
__global__ __launch_bounds__(256) void k_rowsum(const int* __restrict__ hist1,
                                                int* __restrict__ rowtot) {
    int row = blockIdx.x * 4 + (threadIdx.x >> 6);
    int lane = threadIdx.x & 63;
    if (row >= NB1) return;
    int s = 0;
    for (int k = lane; k < NBLK; k += 64) s += hist1[row * NBLK + k];
#pragma unroll
    for (int m = 1; m < 64; m <<= 1) s += __shfl_xor(s, m);
    if (lane == 0) rowtot[row] = s;
}

// ---------------- P2b: small single-block scan of 782 row totals ----------------
__global__ __launch_bounds__(1024) void k_scanb(const int* __restrict__ rowtot,
                                                int* __restrict__ rowbase,
                                                int* __restrict__ bb) {
    __shared__ int sums[1024];
    int t = threadIdx.x;
    int v = (t < NB1) ? rowtot[t] : 0;
    sums[t] = v;
    __syncthreads();
    for (int d = 1; d < 1024; d <<= 1) {
        int u = (t >= d) ? sums[t - d] : 0;
        __syncthreads();
        sums[t] += u;
        __syncthreads();
    }
    if (t < NB1) {
        int base = sums[t] - v;   // exclusive
        rowbase[t] = base;
        bb[t] = base;
    }
    if (t == 0) bb[NB1] = NE;
}

// ---------------- P2c: per-row exclusive scan (one wave per row) ----------------
__global__ __launch_bounds__(256) void k_rowscan(int* __restrict__ hist1,
                                                 const int* __restrict__ rowbase) {
    int row = blockIdx.x * 4 + (threadIdx.x >> 6);
    int lane = threadIdx.x & 63;
    if (row >= NB1) return;
    int carry = rowbase[row];
    for (int k0 = 0; k0 < NBLK; k0 += 64) {
        int k = k0 + lane;
        int v = (k < NBLK) ? hist1[row * NBLK + k] : 0;
        int xv = v;
#pragma unroll
        for (int m = 1; m < 64; m <<= 1) {
            int y = __shfl_up(xv, m);
            if (lane >= m) xv += y;
        }
        int tot = __shfl(xv, 63);
        if (k < NBLK) hist1[row * NBLK + k] = xv - v + carry;
        carry += tot;
    }
}

// ---------------- P3: scatter into coarse buckets (LDS cursors) ----------------
__global__ __launch_bounds__(256) void k_scat(const int* __restrict__ src,
                                              const int* __restrict__ dst,
                                              const int* __restrict__ hist1,
                                              int* __restrict__ packed) {
    __shared__ int cur[NB1];
    for (int i = threadIdx.x; i < NB1; i += 256)
        cur[i] = hist1[i * NBLK + blockIdx.x];
    __syncthreads();
    int base = blockIdx.x * CHUNK;
    int end = min(base + CHUNK, NE);
    for (int e = base + threadIdx.x; e < end; e += 256) {
        int d = dst[e], s = src[e];
        int p = atomicAdd(&cur[d >> 7], 1);
        packed[p] = ((d & 127) << 17) | s;   // src < 2^17
    }
}

// ---------------- P4: within-bucket group by exact dst; emit neigh + off ----------------
__global__ __launch_bounds__(256) void k_bucket(const int* __restrict__ packed,
                                                const int* __restrict__ bb,
                                                int* __restrict__ neigh,
                                                int* __restrict__ off) {
    int b = blockIdx.x;
    int lo = bb[b], hi = bb[b + 1];
    __shared__ int cnt[128];
    __shared__ int pos[128];
    __shared__ int cur2[128];
    if (threadIdx.x < 128) cnt[threadIdx.x] = 0;
    __syncthreads();
    for (int i = lo + threadIdx.x; i < hi; i += 256)
        atomicAdd(&cnt[packed[i] >> 17], 1);
    __syncthreads();
    if (threadIdx.x == 0) {
        int run = lo;
        for (int j = 0; j < 128; ++j) { pos[j] = run; run += cnt[j]; }
    }
    __syncthreads();
    if (threadIdx.x < 128) {
        int node = b * 128 + threadIdx.x;
        if (node <= NN) off[node] = pos[threadIdx.x];
        cur2[threadIdx.x] = pos[threadIdx.x];
    }
    __syncthreads();
    for (int i = lo + threadIdx.x; i < hi; i += 256) {
        int p = packed[i];
        int j = p >> 17;
        int q = atomicAdd(&cur2[j], 1);
        neigh[q] = p & 0x1FFFF;
    }
}

// ---------------- layer 1: CSR mean-agg (d=3) + transform, fused ----------------
__global__ __launch_bounds__(256) void k_l1(const int* __restrict__ off,
                                            const int* __restrict__ neigh,
                                            const float* __restrict__ x,
                                            const float* __restrict__ Wl,
                                            const float* __restrict__ bl,
                                            const float* __restrict__ Wr,
                                            float* __restrict__ out) {
    int n = blockIdx.x * 4 + (threadIdx.x >> 6);
    int c = threadIdx.x & 63;
    if (n >= NN) return;
    int lo = off[n], hi = off[n + 1];
    float a0 = 0.f, a1 = 0.f, a2 = 0.f;
    for (int i = lo + c; i < hi; i += 64) {
        int s = neigh[i];
        a0 += x[s * 3 + 0];
        a1 += x[s * 3 + 1];
        a2 += x[s * 3 + 2];
    }
#pragma unroll
    for (int m = 1; m < 64; m <<= 1) {
        a0 += __shfl_xor(a0, m);
        a1 += __shfl_xor(a1, m);
        a2 += __shfl_xor(a2, m);
    }
    float ic = 1.0f / fmaxf((float)(hi - lo), 1.0f);
    a0 *= ic; a1 *= ic; a2 *= ic;
    float x0 = x[n * 3 + 0], x1 = x[n * 3 + 1], x2 = x[n * 3 + 2];
    float acc = bl[c]
              + a0 * Wl[0 * 64 + c] + a1 * Wl[1 * 64 + c] + a2 * Wl[2 * 64 + c]
              + x0 * Wr[0 * 64 + c] + x1 * Wr[1 * 64 + c] + x2 * Wr[2 * 64 + c];
    out[n * 64 + c] = fmaxf(acc, 0.0f);
}

// ---------------- fused layer: CSR mean-agg (d=64) + transform + relu ----------------
// out must not alias h (reads h[s] for arbitrary s while writing out rows)
__global__ __launch_bounds__(256) void k_layer(const int* __restrict__ off,
                                               const int* __restrict__ neigh,
                                               const float* __restrict__ h,
                                               const float* __restrict__ Wl,
                                               const float* __restrict__ bl,
                                               const float* __restrict__ Wr,
                                               float* __restrict__ out) {
    __shared__ float Ws[2][64 * 64];   // 32 KiB: Wl, Wr
    __shared__ float rows[2][4][64];   // mean row, h row per wave
    for (int i = threadIdx.x; i < 64 * 64; i += 256) {
        Ws[0][i] = Wl[i];
        Ws[1][i] = Wr[i];
    }
    int li = threadIdx.x >> 6;
    int lane = threadIdx.x & 63;
    int n = blockIdx.x * 4 + li;
    if (n < NN) {
        int lo = off[n], hi = off[n + 1];
        float acc = 0.f;
        int i = lo;
        for (; i + 8 <= hi; i += 8) {
            int s0 = neigh[i + 0], s1 = neigh[i + 1], s2 = neigh[i + 2], s3 = neigh[i + 3];
            int s4 = neigh[i + 4], s5 = neigh[i + 5], s6 = neigh[i + 6], s7 = neigh[i + 7];
            float v0 = h[(size_t)s0 * 64 + lane];
            float v1 = h[(size_t)s1 * 64 + lane];
            float v2 = h[(size_t)s2 * 64 + lane];
            float v3 = h[(size_t)s3 * 64 + lane];
            float v4 = h[(size_t)s4 * 64 + lane];
            float v5 = h[(size_t)s5 * 64 + lane];
            float v6 = h[(size_t)s6 * 64 + lane];
            float v7 = h[(size_t)s7 * 64 + lane];
            acc += ((v0 + v1) + (v2 + v3)) + ((v4 + v5) + (v6 + v7));
        }
        for (; i < hi; ++i)
            acc += h[(size_t)neigh[i] * 64 + lane];
        float ic = 1.0f / fmaxf((float)(hi - lo), 1.0f);
        rows[0][li][lane] = acc * ic;
        rows[1][li][lane] = h[(size_t)n * 64 + lane];
    }
    __syncthreads();
    if (n >= NN) return;
    float o = bl[lane];
#pragma unroll 8
    for (int k = 0; k < 64; ++k) {
        o += rows[0][li][k] * Ws[0][k * 64 + lane] + rows[1][li][k] * Ws[1][k * 64 + lane];
    }
    out[(size_t)n * 64 + lane] = fmaxf(o, 0.0f);
}

// ---------------- pooling helpers ----------------
__device__ __forceinline__ int lower_bound_batch(const int* __restrict__ batch, int val) {
    int lo = 0, hi = NN;
    while (lo < hi) {
        int mid = (lo + hi) >> 1;
        if (batch[mid] < val) lo = mid + 1; else hi = mid;
    }
    return lo;
}

__global__ __launch_bounds__(64) void k_pool(const float* __restrict__ h,
                                             const int* __restrict__ batch,
                                             float* __restrict__ psum) {
    int g = blockIdx.x >> 3;
    int part = blockIdx.x & 7;
    int lane = threadIdx.x;
    int lo = lower_bound_batch(batch, g);
    int hi = lower_bound_batch(batch, g + 1);
    float s = 0.0f;
    for (int n = lo + part; n < hi; n += 8) s += h[n * 64 + lane];
    atomicAdd(&psum[g * 64 + lane], s);
}

__global__ __launch_bounds__(128) void k_fc(const float* __restrict__ psum,
                                            const int* __restrict__ batch,
                                            const float* __restrict__ Wfc,
                                            const float* __restrict__ bfc,
                                            float* __restrict__ out) {
    __shared__ float meanv[64];
    __shared__ float red[2];
    int g = blockIdx.x;
    int c = threadIdx.x;
    int lo = lower_bound_batch(batch, g);
    int hi = lower_bound_batch(batch, g + 1);
    float icnt = 1.0f / fmaxf((float)(hi - lo), 1.0f);
    if (c < 64) meanv[c] = psum[g * 64 + c] * icnt;
    __syncthreads();
    float acc = bfc[c];
#pragma unroll
    for (int k = 0; k < 64; ++k) acc += meanv[k] * Wfc[k * 128 + c];
    float ss = acc * acc;
#pragma unroll
    for (int off = 32; off; off >>= 1) ss += __shfl_down(ss, off);
    if ((c & 63) == 0) red[c >> 6] = ss;
    __syncthreads();
    float norm = fmaxf(sqrtf(red[0] + red[1]), 1e-12f);
    out[g * 128 + c] = acc / norm;
}

extern "C" void kernel_launch(void* const* d_in, const int* in_sizes, int n_in,
                              void* d_out, int out_size, void* d_ws, size_t ws_size,
                              hipStream_t stream) {
    const float* x    = (const float*)d_in[0];
    const int*   ei   = (const int*)d_in[1];
    const int*   src  = ei;
    const int*   dst  = ei + NE;
    const int*   batch = (const int*)d_in[2];
    const float* Wl1 = (const float*)d_in[3];
    const float* bl1 = (const float*)d_in[4];
    const float* Wr1 = (const float*)d_in[5];
    const float* Wl2 = (const float*)d_in[6];
    const float* bl2 = (const float*)d_in[7];
    const float* Wr2 = (const float*)d_in[8];
    const float* Wl3 = (const float*)d_in[9];
    const float* bl3 = (const float*)d_in[10];
    const float* Wr3 = (const float*)d_in[11];
    const float* Wl4 = (const float*)d_in[12];
    const float* bl4 = (const float*)d_in[13];
    const float* Wr4 = (const float*)d_in[14];
    const float* Wfc = (const float*)d_in[15];
    const float* bfc = (const float*)d_in[16];
    float* out = (float*)d_out;

    // workspace layout
    float* hA    = (float*)d_ws;                     // [N,64]
    float* hB    = hA + (size_t)NN * 64;             // [N,64]
    float* psum  = hB + (size_t)NN * 64;             // [G,64]
    int*   off   = (int*)(psum + (size_t)NG * 64);   // [N+1]
    int*   bb    = off + NN + 1;                     // [NB1+1]
    int*   rowtot = bb + NB1 + 1;                    // [NB1]
    int*   rowbase = rowtot + NB1;                   // [NB1]
    int*   hist1 = rowbase + NB1;                    // [NB1*NBLK]
    int*   packed = hist1 + NB1 * NBLK;              // [E]
    int*   neigh  = packed + NE;                     // [E]

    hipMemsetAsync(psum, 0, (size_t)NG * 64 * sizeof(float), stream);

    // CSR build: atomic-free two-level bucket sort, fully parallel scan
    k_hist<<<NBLK, 256, 0, stream>>>(dst, hist1);
    k_rowsum<<<(NB1 + 3) / 4, 256, 0, stream>>>(hist1, rowtot);
    k_scanb<<<1, 1024, 0, stream>>>(rowtot, rowbase, bb);
    k_rowscan<<<(NB1 + 3) / 4, 256, 0, stream>>>(hist1, rowbase);
    k_scat<<<NBLK, 256, 0, stream>>>(src, dst, hist1, packed);
    k_bucket<<<NB1, 256, 0, stream>>>(packed, bb, neigh, off);

    const int nodeGrid = (NN + 3) / 4;

    // layer 1 (fused d=3 agg + transform)
    k_l1<<<nodeGrid, 256, 0, stream>>>(off, neigh, x, Wl1, bl1, Wr1, hA);

    // layers 2-4: fused agg + transform (ping-pong hA/hB)
    k_layer<<<nodeGrid, 256, 0, stream>>>(off, neigh, hA, Wl2, bl2, Wr2, hB);
    k_layer<<<nodeGrid, 256, 0, stream>>>(off, neigh, hB, Wl3, bl3, Wr3, hA);
    k_layer<<<nodeGrid, 256, 0, stream>>>(off, neigh, hA, Wl4, bl4, Wr4, hB);

    k_pool<<<NG * 8, 64, 0, stream>>>(hB, batch, psum);
    k_fc<<<NG, 128, 0, stream>>>(psum, batch, Wfc, bfc, out);
}

// Round 6
// 568.267 us; speedup vs baseline: 5.4409x; 1.4893x over previous
//
#include <hip/hip_runtime.h>

#define NN 100000
#define NE 3200000
#define NG 128
#define HID 64
#define OUTC 128

#define CHUNK 8192
#define NBLK 391                 // ceil(NE / CHUNK)
#define NB1 782                  // ceil(NN / 128) coarse buckets (dst >> 7)

// ---------------- P1: per-block coarse histogram (LDS atomics only) ----------------
__global__ __launch_bounds__(256) void k_hist(const int* __restrict__ dst,
                                              int* __restrict__ hist1) {
    __shared__ int h[NB1];
    for (int i = threadIdx.x; i < NB1; i += 256) h[i] = 0;
    __syncthreads();
    int base = blockIdx.x * CHUNK;
    int end = min(base + CHUNK, NE);
    for (int e = base + threadIdx.x; e < end; e += 256)
        atomicAdd(&h[dst[e] >> 7], 1);
    __syncthreads();
    for (int i = threadIdx.x; i < NB1; i += 256)
        hist1[i * NBLK + blockIdx.x] = h[i];
}

// ---------------- P2a: per-row totals (one wave per row) ----------------
__global__ __launch_bounds__(256) void k_rowsum(const int* __restrict__ hist1,
                                                int* __restrict__ rowtot) {
    int row = blockIdx.x * 4 + (threadIdx.x >> 6);
    int lane = threadIdx.x & 63;
    if (row >= NB1) return;
    int s = 0;
    for (int k = lane; k < NBLK; k += 64) s += hist1[row * NBLK + k];
#pragma unroll
    for (int m = 1; m < 64; m <<= 1) s += __shfl_xor(s, m);
    if (lane == 0) rowtot[row] = s;
}

// ---------------- P2b: small single-block scan of 782 row totals ----------------
__global__ __launch_bounds__(1024) void k_scanb(const int* __restrict__ rowtot,
                                                int* __restrict__ rowbase,
                                                int* __restrict__ bb) {
    __shared__ int sums[1024];
    int t = threadIdx.x;
    int v = (t < NB1) ? rowtot[t] : 0;
    sums[t] = v;
    __syncthreads();
    for (int d = 1; d < 1024; d <<= 1) {
        int u = (t >= d) ? sums[t - d] : 0;
        __syncthreads();
        sums[t] += u;
        __syncthreads();
    }
    if (t < NB1) {
        int base = sums[t] - v;   // exclusive
        rowbase[t] = base;
        bb[t] = base;
    }
    if (t == 0) bb[NB1] = NE;
}

// ---------------- P2c: per-row exclusive scan (one wave per row) ----------------
__global__ __launch_bounds__(256) void k_rowscan(int* __restrict__ hist1,
                                                 const int* __restrict__ rowbase) {
    int row = blockIdx.x * 4 + (threadIdx.x >> 6);
    int lane = threadIdx.x & 63;
    if (row >= NB1) return;
    int carry = rowbase[row];
    for (int k0 = 0; k0 < NBLK; k0 += 64) {
        int k = k0 + lane;
        int v = (k < NBLK) ? hist1[row * NBLK + k] : 0;
        int xv = v;
#pragma unroll
        for (int m = 1; m < 64; m <<= 1) {
            int y = __shfl_up(xv, m);
            if (lane >= m) xv += y;
        }
        int tot = __shfl(xv, 63);
        if (k < NBLK) hist1[row * NBLK + k] = xv - v + carry;
        carry += tot;
    }
}

// ---------------- P3: scatter into coarse buckets (LDS cursors) ----------------
__global__ __launch_bounds__(256) void k_scat(const int* __restrict__ src,
                                              const int* __restrict__ dst,
                                              const int* __restrict__ hist1,
                                              int* __restrict__ packed) {
    __shared__ int cur[NB1];
    for (int i = threadIdx.x; i < NB1; i += 256)
        cur[i] = hist1[i * NBLK + blockIdx.x];
    __syncthreads();
    int base = blockIdx.x * CHUNK;
    int end = min(base + CHUNK, NE);
    for (int e = base + threadIdx.x; e < end; e += 256) {
        int d = dst[e], s = src[e];
        int p = atomicAdd(&cur[d >> 7], 1);
        packed[p] = ((d & 127) << 17) | s;   // src < 2^17
    }
}

// ---------------- P4: within-bucket group by exact dst; emit neigh + off ----------------
__global__ __launch_bounds__(256) void k_bucket(const int* __restrict__ packed,
                                                const int* __restrict__ bb,
                                                int* __restrict__ neigh,
                                                int* __restrict__ off) {
    int b = blockIdx.x;
    int lo = bb[b], hi = bb[b + 1];
    __shared__ int cnt[128];
    __shared__ int pos[128];
    __shared__ int cur2[128];
    if (threadIdx.x < 128) cnt[threadIdx.x] = 0;
    __syncthreads();
    for (int i = lo + threadIdx.x; i < hi; i += 256)
        atomicAdd(&cnt[packed[i] >> 17], 1);
    __syncthreads();
    if (threadIdx.x == 0) {
        int run = lo;
        for (int j = 0; j < 128; ++j) { pos[j] = run; run += cnt[j]; }
    }
    __syncthreads();
    if (threadIdx.x < 128) {
        int node = b * 128 + threadIdx.x;
        if (node <= NN) off[node] = pos[threadIdx.x];
        cur2[threadIdx.x] = pos[threadIdx.x];
    }
    __syncthreads();
    for (int i = lo + threadIdx.x; i < hi; i += 256) {
        int p = packed[i];
        int j = p >> 17;
        int q = atomicAdd(&cur2[j], 1);
        neigh[q] = p & 0x1FFFF;
    }
}

// ---------------- layer 1: CSR mean-agg (d=3) + transform, fused ----------------
__global__ __launch_bounds__(256) void k_l1(const int* __restrict__ off,
                                            const int* __restrict__ neigh,
                                            const float* __restrict__ x,
                                            const float* __restrict__ Wl,
                                            const float* __restrict__ bl,
                                            const float* __restrict__ Wr,
                                            float* __restrict__ out) {
    int n = blockIdx.x * 4 + (threadIdx.x >> 6);
    int c = threadIdx.x & 63;
    if (n >= NN) return;
    int lo = off[n], hi = off[n + 1];
    float a0 = 0.f, a1 = 0.f, a2 = 0.f;
    for (int i = lo + c; i < hi; i += 64) {
        int s = neigh[i];
        a0 += x[s * 3 + 0];
        a1 += x[s * 3 + 1];
        a2 += x[s * 3 + 2];
    }
#pragma unroll
    for (int m = 1; m < 64; m <<= 1) {
        a0 += __shfl_xor(a0, m);
        a1 += __shfl_xor(a1, m);
        a2 += __shfl_xor(a2, m);
    }
    float ic = 1.0f / fmaxf((float)(hi - lo), 1.0f);
    a0 *= ic; a1 *= ic; a2 *= ic;
    float x0 = x[n * 3 + 0], x1 = x[n * 3 + 1], x2 = x[n * 3 + 2];
    float acc = bl[c]
              + a0 * Wl[0 * 64 + c] + a1 * Wl[1 * 64 + c] + a2 * Wl[2 * 64 + c]
              + x0 * Wr[0 * 64 + c] + x1 * Wr[1 * 64 + c] + x2 * Wr[2 * 64 + c];
    out[n * 64 + c] = fmaxf(acc, 0.0f);
}

// ---------------- fused layer: CSR mean-agg (d=64) + transform + relu ----------------
// 8 waves/block = 8 nodes/block; scalarized gather addressing; single barrier.
// out must not alias h.
__global__ __launch_bounds__(512, 8) void k_layer(const int* __restrict__ off,
                                                  const int* __restrict__ neigh,
                                                  const float* __restrict__ h,
                                                  const float* __restrict__ Wl,
                                                  const float* __restrict__ bl,
                                                  const float* __restrict__ Wr,
                                                  float* __restrict__ out) {
    __shared__ float Ws[2][64 * 64];   // 32 KiB: Wl, Wr
    __shared__ float rows[2][8][64];   // mean row, h row per wave (wave-private slots)
    for (int i = threadIdx.x; i < 64 * 64; i += 512) {
        Ws[0][i] = Wl[i];
        Ws[1][i] = Wr[i];
    }
    __syncthreads();                   // the ONLY barrier: Ws ready before matvec

    int li = threadIdx.x >> 6;
    int lane = threadIdx.x & 63;
    int n = blockIdx.x * 8 + li;       // grid is exact: NN/8 = 12500
    if (n >= NN) return;

    // wave-uniform bounds -> scalar loads for neigh, SALU addressing for rows
    int lo = __builtin_amdgcn_readfirstlane(off[n]);
    int hi = __builtin_amdgcn_readfirstlane(off[n + 1]);
    int deg = hi - lo;
    const int* __restrict__ np = neigh + lo;

    float racc = h[(size_t)n * 64 + lane];   // root row (overlaps with gather)
    float acc0 = 0.f, acc1 = 0.f;
    int i = 0;
    for (; i + 8 <= deg; i += 8) {
        int s0 = np[i + 0], s1 = np[i + 1], s2 = np[i + 2], s3 = np[i + 3];
        int s4 = np[i + 4], s5 = np[i + 5], s6 = np[i + 6], s7 = np[i + 7];
        float v0 = h[(size_t)s0 * 64 + lane];
        float v1 = h[(size_t)s1 * 64 + lane];
        float v2 = h[(size_t)s2 * 64 + lane];
        float v3 = h[(size_t)s3 * 64 + lane];
        float v4 = h[(size_t)s4 * 64 + lane];
        float v5 = h[(size_t)s5 * 64 + lane];
        float v6 = h[(size_t)s6 * 64 + lane];
        float v7 = h[(size_t)s7 * 64 + lane];
        acc0 += (v0 + v1) + (v2 + v3);
        acc1 += (v4 + v5) + (v6 + v7);
    }
    for (; i < deg; ++i)
        acc0 += h[(size_t)np[i] * 64 + lane];
    float ic = 1.0f / fmaxf((float)deg, 1.0f);

    // wave-private LDS slot: same-wave ds_write -> ds_read, no block barrier needed
    rows[0][li][lane] = (acc0 + acc1) * ic;
    rows[1][li][lane] = racc;

    float o = bl[lane];
#pragma unroll 8
    for (int k = 0; k < 64; ++k) {
        o += rows[0][li][k] * Ws[0][k * 64 + lane] + rows[1][li][k] * Ws[1][k * 64 + lane];
    }
    out[(size_t)n * 64 + lane] = fmaxf(o, 0.0f);
}

// ---------------- pooling helpers ----------------
__device__ __forceinline__ int lower_bound_batch(const int* __restrict__ batch, int val) {
    int lo = 0, hi = NN;
    while (lo < hi) {
        int mid = (lo + hi) >> 1;
        if (batch[mid] < val) lo = mid + 1; else hi = mid;
    }
    return lo;
}

__global__ __launch_bounds__(64) void k_pool(const float* __restrict__ h,
                                             const int* __restrict__ batch,
                                             float* __restrict__ psum) {
    int g = blockIdx.x >> 3;
    int part = blockIdx.x & 7;
    int lane = threadIdx.x;
    int lo = lower_bound_batch(batch, g);
    int hi = lower_bound_batch(batch, g + 1);
    float s = 0.0f;
    for (int n = lo + part; n < hi; n += 8) s += h[n * 64 + lane];
    atomicAdd(&psum[g * 64 + lane], s);
}

__global__ __launch_bounds__(128) void k_fc(const float* __restrict__ psum,
                                            const int* __restrict__ batch,
                                            const float* __restrict__ Wfc,
                                            const float* __restrict__ bfc,
                                            float* __restrict__ out) {
    __shared__ float meanv[64];
    __shared__ float red[2];
    int g = blockIdx.x;
    int c = threadIdx.x;
    int lo = lower_bound_batch(batch, g);
    int hi = lower_bound_batch(batch, g + 1);
    float icnt = 1.0f / fmaxf((float)(hi - lo), 1.0f);
    if (c < 64) meanv[c] = psum[g * 64 + c] * icnt;
    __syncthreads();
    float acc = bfc[c];
#pragma unroll
    for (int k = 0; k < 64; ++k) acc += meanv[k] * Wfc[k * 128 + c];
    float ss = acc * acc;
#pragma unroll
    for (int off = 32; off; off >>= 1) ss += __shfl_down(ss, off);
    if ((c & 63) == 0) red[c >> 6] = ss;
    __syncthreads();
    float norm = fmaxf(sqrtf(red[0] + red[1]), 1e-12f);
    out[g * 128 + c] = acc / norm;
}

extern "C" void kernel_launch(void* const* d_in, const int* in_sizes, int n_in,
                              void* d_out, int out_size, void* d_ws, size_t ws_size,
                              hipStream_t stream) {
    const float* x    = (const float*)d_in[0];
    const int*   ei   = (const int*)d_in[1];
    const int*   src  = ei;
    const int*   dst  = ei + NE;
    const int*   batch = (const int*)d_in[2];
    const float* Wl1 = (const float*)d_in[3];
    const float* bl1 = (const float*)d_in[4];
    const float* Wr1 = (const float*)d_in[5];
    const float* Wl2 = (const float*)d_in[6];
    const float* bl2 = (const float*)d_in[7];
    const float* Wr2 = (const float*)d_in[8];
    const float* Wl3 = (const float*)d_in[9];
    const float* bl3 = (const float*)d_in[10];
    const float* Wr3 = (const float*)d_in[11];
    const float* Wl4 = (const float*)d_in[12];
    const float* bl4 = (const float*)d_in[13];
    const float* Wr4 = (const float*)d_in[14];
    const float* Wfc = (const float*)d_in[15];
    const float* bfc = (const float*)d_in[16];
    float* out = (float*)d_out;

    // workspace layout
    float* hA    = (float*)d_ws;                     // [N,64]
    float* hB    = hA + (size_t)NN * 64;             // [N,64]
    float* psum  = hB + (size_t)NN * 64;             // [G,64]
    int*   off   = (int*)(psum + (size_t)NG * 64);   // [N+1]
    int*   bb    = off + NN + 1;                     // [NB1+1]
    int*   rowtot = bb + NB1 + 1;                    // [NB1]
    int*   rowbase = rowtot + NB1;                   // [NB1]
    int*   hist1 = rowbase + NB1;                    // [NB1*NBLK]
    int*   packed = hist1 + NB1 * NBLK;              // [E]
    int*   neigh  = packed + NE;                     // [E]

    hipMemsetAsync(psum, 0, (size_t)NG * 64 * sizeof(float), stream);

    // CSR build: atomic-free two-level bucket sort, fully parallel scan
    k_hist<<<NBLK, 256, 0, stream>>>(dst, hist1);
    k_rowsum<<<(NB1 + 3) / 4, 256, 0, stream>>>(hist1, rowtot);
    k_scanb<<<1, 1024, 0, stream>>>(rowtot, rowbase, bb);
    k_rowscan<<<(NB1 + 3) / 4, 256, 0, stream>>>(hist1, rowbase);
    k_scat<<<NBLK, 256, 0, stream>>>(src, dst, hist1, packed);
    k_bucket<<<NB1, 256, 0, stream>>>(packed, bb, neigh, off);

    // layer 1 (fused d=3 agg + transform)
    k_l1<<<(NN + 3) / 4, 256, 0, stream>>>(off, neigh, x, Wl1, bl1, Wr1, hA);

    // layers 2-4: fused agg + transform (ping-pong hA/hB), 8 nodes/block
    const int layerGrid = (NN + 7) / 8;
    k_layer<<<layerGrid, 512, 0, stream>>>(off, neigh, hA, Wl2, bl2, Wr2, hB);
    k_layer<<<layerGrid, 512, 0, stream>>>(off, neigh, hB, Wl3, bl3, Wr3, hA);
    k_layer<<<layerGrid, 512, 0, stream>>>(off, neigh, hA, Wl4, bl4, Wr4, hB);

    k_pool<<<NG * 8, 64, 0, stream>>>(hB, batch, psum);
    k_fc<<<NG, 128, 0, stream>>>(psum, batch, Wfc, bfc, out);
}

// Round 7
// 447.918 us; speedup vs baseline: 6.9028x; 1.2687x over previous
//
#include <hip/hip_runtime.h>

#define NN 100000
#define NE 3200000
#define NG 128
#define HID 64
#define OUTC 128

#define CHUNK 8192
#define NBLK 391                 // ceil(NE / CHUNK)
#define NB1 782                  // ceil(NN / 128) coarse buckets (dst >> 7)

typedef _Float16 half2v __attribute__((ext_vector_type(2)));

#if __has_builtin(__builtin_amdgcn_fdot2)
#define FDOT2(a, b, c) __builtin_amdgcn_fdot2((a), (b), (c), false)
#else
#define FDOT2(a, b, c) ((c) + (float)(a).x * (float)(b).x + (float)(a).y * (float)(b).y)
#endif

// ---------------- P1: per-block coarse histogram (LDS atomics only) ----------------
__global__ __launch_bounds__(256) void k_hist(const int* __restrict__ dst,
                                              int* __restrict__ hist1) {
    __shared__ int h[NB1];
    for (int i = threadIdx.x; i < NB1; i += 256) h[i] = 0;
    __syncthreads();
    int base = blockIdx.x * CHUNK;
    int end = min(base + CHUNK, NE);
    for (int e = base + threadIdx.x; e < end; e += 256)
        atomicAdd(&h[dst[e] >> 7], 1);
    __syncthreads();
    for (int i = threadIdx.x; i < NB1; i += 256)
        hist1[i * NBLK + blockIdx.x] = h[i];
}

// ---------------- P2a: per-row totals (one wave per row) ----------------
__global__ __launch_bounds__(256) void k_rowsum(const int* __restrict__ hist1,
                                                int* __restrict__ rowtot) {
    int row = blockIdx.x * 4 + (threadIdx.x >> 6);
    int lane = threadIdx.x & 63;
    if (row >= NB1) return;
    int s = 0;
    for (int k = lane; k < NBLK; k += 64) s += hist1[row * NBLK + k];
#pragma unroll
    for (int m = 1; m < 64; m <<= 1) s += __shfl_xor(s, m);
    if (lane == 0) rowtot[row] = s;
}

// ---------------- P2b: small single-block scan of 782 row totals ----------------
__global__ __launch_bounds__(1024) void k_scanb(const int* __restrict__ rowtot,
                                                int* __restrict__ rowbase,
                                                int* __restrict__ bb) {
    __shared__ int sums[1024];
    int t = threadIdx.x;
    int v = (t < NB1) ? rowtot[t] : 0;
    sums[t] = v;
    __syncthreads();
    for (int d = 1; d < 1024; d <<= 1) {
        int u = (t >= d) ? sums[t - d] : 0;
        __syncthreads();
        sums[t] += u;
        __syncthreads();
    }
    if (t < NB1) {
        int base = sums[t] - v;   // exclusive
        rowbase[t] = base;
        bb[t] = base;
    }
    if (t == 0) bb[NB1] = NE;
}

// ---------------- P2c: per-row exclusive scan (one wave per row) ----------------
__global__ __launch_bounds__(256) void k_rowscan(int* __restrict__ hist1,
                                                 const int* __restrict__ rowbase) {
    int row = blockIdx.x * 4 + (threadIdx.x >> 6);
    int lane = threadIdx.x & 63;
    if (row >= NB1) return;
    int carry = rowbase[row];
    for (int k0 = 0; k0 < NBLK; k0 += 64) {
        int k = k0 + lane;
        int v = (k < NBLK) ? hist1[row * NBLK + k] : 0;
        int xv = v;
#pragma unroll
        for (int m = 1; m < 64; m <<= 1) {
            int y = __shfl_up(xv, m);
            if (lane >= m) xv += y;
        }
        int tot = __shfl(xv, 63);
        if (k < NBLK) hist1[row * NBLK + k] = xv - v + carry;
        carry += tot;
    }
}

// ---------------- P3: scatter into coarse buckets (LDS cursors) ----------------
__global__ __launch_bounds__(256) void k_scat(const int* __restrict__ src,
                                              const int* __restrict__ dst,
                                              const int* __restrict__ hist1,
                                              int* __restrict__ packed) {
    __shared__ int cur[NB1];
    for (int i = threadIdx.x; i < NB1; i += 256)
        cur[i] = hist1[i * NBLK + blockIdx.x];
    __syncthreads();
    int base = blockIdx.x * CHUNK;
    int end = min(base + CHUNK, NE);
    for (int e = base + threadIdx.x; e < end; e += 256) {
        int d = dst[e], s = src[e];
        int p = atomicAdd(&cur[d >> 7], 1);
        packed[p] = ((d & 127) << 17) | s;   // src < 2^17
    }
}

// ---------------- P4: within-bucket group by exact dst; emit neigh + off ----------------
__global__ __launch_bounds__(256) void k_bucket(const int* __restrict__ packed,
                                                const int* __restrict__ bb,
                                                int* __restrict__ neigh,
                                                int* __restrict__ off) {
    int b = blockIdx.x;
    int lo = bb[b], hi = bb[b + 1];
    __shared__ int cnt[128];
    __shared__ int pos[128];
    __shared__ int cur2[128];
    if (threadIdx.x < 128) cnt[threadIdx.x] = 0;
    __syncthreads();
    for (int i = lo + threadIdx.x; i < hi; i += 256)
        atomicAdd(&cnt[packed[i] >> 17], 1);
    __syncthreads();
    if (threadIdx.x == 0) {
        int run = lo;
        for (int j = 0; j < 128; ++j) { pos[j] = run; run += cnt[j]; }
    }
    __syncthreads();
    if (threadIdx.x < 128) {
        int node = b * 128 + threadIdx.x;
        if (node <= NN) off[node] = pos[threadIdx.x];
        cur2[threadIdx.x] = pos[threadIdx.x];
    }
    __syncthreads();
    for (int i = lo + threadIdx.x; i < hi; i += 256) {
        int p = packed[i];
        int j = p >> 17;
        int q = atomicAdd(&cur2[j], 1);
        neigh[q] = p & 0x1FFFF;
    }
}

// ---------------- layer 1: CSR mean-agg (d=3) + transform, fp16 out ----------------
__global__ __launch_bounds__(256) void k_l1(const int* __restrict__ off,
                                            const int* __restrict__ neigh,
                                            const float* __restrict__ x,
                                            const float* __restrict__ Wl,
                                            const float* __restrict__ bl,
                                            const float* __restrict__ Wr,
                                            _Float16* __restrict__ out) {
    int n = blockIdx.x * 4 + (threadIdx.x >> 6);
    int c = threadIdx.x & 63;
    if (n >= NN) return;
    int lo = off[n], hi = off[n + 1];
    float a0 = 0.f, a1 = 0.f, a2 = 0.f;
    for (int i = lo + c; i < hi; i += 64) {
        int s = neigh[i];
        a0 += x[s * 3 + 0];
        a1 += x[s * 3 + 1];
        a2 += x[s * 3 + 2];
    }
#pragma unroll
    for (int m = 1; m < 64; m <<= 1) {
        a0 += __shfl_xor(a0, m);
        a1 += __shfl_xor(a1, m);
        a2 += __shfl_xor(a2, m);
    }
    float ic = 1.0f / fmaxf((float)(hi - lo), 1.0f);
    a0 *= ic; a1 *= ic; a2 *= ic;
    float x0 = x[n * 3 + 0], x1 = x[n * 3 + 1], x2 = x[n * 3 + 2];
    float acc = bl[c]
              + a0 * Wl[0 * 64 + c] + a1 * Wl[1 * 64 + c] + a2 * Wl[2 * 64 + c]
              + x0 * Wr[0 * 64 + c] + x1 * Wr[1 * 64 + c] + x2 * Wr[2 * 64 + c];
    out[(size_t)n * 64 + c] = (_Float16)fmaxf(acc, 0.0f);
}

// ---------------- fused layer: fp16 pair-gather + dot2 matvec ----------------
// h: half2-packed [NN][32]; out: fp16 [NN][64]. out must not alias h.
__global__ __launch_bounds__(512, 8) void k_layer(const int* __restrict__ off,
                                                  const int* __restrict__ neigh,
                                                  const half2v* __restrict__ h,
                                                  const float* __restrict__ Wl,
                                                  const float* __restrict__ bl,
                                                  const float* __restrict__ Wr,
                                                  _Float16* __restrict__ out) {
    __shared__ half2v Wpk[2][32][64];     // 16 KiB: k-pair packed Wl, Wr
    __shared__ half2v rowspk[2][8][32];   // mean row, root row per wave (half2/kp)
    for (int idx = threadIdx.x; idx < 32 * 64; idx += 512) {
        int kp = idx >> 6, c = idx & 63;
        Wpk[0][kp][c] = half2v{(_Float16)Wl[(2 * kp) * 64 + c],
                               (_Float16)Wl[(2 * kp + 1) * 64 + c]};
        Wpk[1][kp][c] = half2v{(_Float16)Wr[(2 * kp) * 64 + c],
                               (_Float16)Wr[(2 * kp + 1) * 64 + c]};
    }
    __syncthreads();                      // only barrier: Wpk ready

    int li = threadIdx.x >> 6;
    int lane = threadIdx.x & 63;
    int kp = lane & 31;
    int n = blockIdx.x * 8 + li;          // grid exact: 12500*8 = NN
    if (n >= NN) return;

    int lo = __builtin_amdgcn_readfirstlane(off[n]);
    int hi = __builtin_amdgcn_readfirstlane(off[n + 1]);
    int deg = hi - lo;
    const int* __restrict__ np = neigh + lo;

    // pair-mode gather: lanes 0-31 -> neighbor 2i, lanes 32-63 -> neighbor 2i+1
    float a0 = 0.f, a1 = 0.f;
    int npairs = deg >> 1;
#pragma unroll 4
    for (int i = 0; i < npairs; ++i) {
        int s0 = np[2 * i];
        int s1 = np[2 * i + 1];
        int s = (lane < 32) ? s0 : s1;
        half2v v = h[(size_t)s * 32 + kp];
        a0 += (float)v.x;
        a1 += (float)v.y;
    }
    if (deg & 1) {
        int s = np[deg - 1];
        half2v v = h[(size_t)s * 32 + kp];
        if (lane < 32) { a0 += (float)v.x; a1 += (float)v.y; }
    }
    a0 += __shfl_xor(a0, 32);
    a1 += __shfl_xor(a1, 32);

    if (lane < 32) {
        float ic = 1.0f / fmaxf((float)deg, 1.0f);
        rowspk[0][li][kp] = half2v{(_Float16)(a0 * ic), (_Float16)(a1 * ic)};
        rowspk[1][li][kp] = h[(size_t)n * 32 + kp];   // root row
    }
    // same-wave ds_write -> ds_read: compiler inserts lgkmcnt wait; no barrier

    float o = bl[lane];
#pragma unroll
    for (int k2 = 0; k2 < 32; ++k2) {
        o = FDOT2(rowspk[0][li][k2], Wpk[0][k2][lane], o);
        o = FDOT2(rowspk[1][li][k2], Wpk[1][k2][lane], o);
    }
    out[(size_t)n * 64 + lane] = (_Float16)fmaxf(o, 0.0f);
}

// ---------------- pooling helpers ----------------
__device__ __forceinline__ int lower_bound_batch(const int* __restrict__ batch, int val) {
    int lo = 0, hi = NN;
    while (lo < hi) {
        int mid = (lo + hi) >> 1;
        if (batch[mid] < val) lo = mid + 1; else hi = mid;
    }
    return lo;
}

__global__ __launch_bounds__(64) void k_pool(const _Float16* __restrict__ h,
                                             const int* __restrict__ batch,
                                             float* __restrict__ psum) {
    int g = blockIdx.x >> 3;
    int part = blockIdx.x & 7;
    int lane = threadIdx.x;
    int lo = lower_bound_batch(batch, g);
    int hi = lower_bound_batch(batch, g + 1);
    float s = 0.0f;
    for (int n = lo + part; n < hi; n += 8) s += (float)h[(size_t)n * 64 + lane];
    atomicAdd(&psum[g * 64 + lane], s);
}

__global__ __launch_bounds__(128) void k_fc(const float* __restrict__ psum,
                                            const int* __restrict__ batch,
                                            const float* __restrict__ Wfc,
                                            const float* __restrict__ bfc,
                                            float* __restrict__ out) {
    __shared__ float meanv[64];
    __shared__ float red[2];
    int g = blockIdx.x;
    int c = threadIdx.x;
    int lo = lower_bound_batch(batch, g);
    int hi = lower_bound_batch(batch, g + 1);
    float icnt = 1.0f / fmaxf((float)(hi - lo), 1.0f);
    if (c < 64) meanv[c] = psum[g * 64 + c] * icnt;
    __syncthreads();
    float acc = bfc[c];
#pragma unroll
    for (int k = 0; k < 64; ++k) acc += meanv[k] * Wfc[k * 128 + c];
    float ss = acc * acc;
#pragma unroll
    for (int off = 32; off; off >>= 1) ss += __shfl_down(ss, off);
    if ((c & 63) == 0) red[c >> 6] = ss;
    __syncthreads();
    float norm = fmaxf(sqrtf(red[0] + red[1]), 1e-12f);
    out[g * 128 + c] = acc / norm;
}

extern "C" void kernel_launch(void* const* d_in, const int* in_sizes, int n_in,
                              void* d_out, int out_size, void* d_ws, size_t ws_size,
                              hipStream_t stream) {
    const float* x    = (const float*)d_in[0];
    const int*   ei   = (const int*)d_in[1];
    const int*   src  = ei;
    const int*   dst  = ei + NE;
    const int*   batch = (const int*)d_in[2];
    const float* Wl1 = (const float*)d_in[3];
    const float* bl1 = (const float*)d_in[4];
    const float* Wr1 = (const float*)d_in[5];
    const float* Wl2 = (const float*)d_in[6];
    const float* bl2 = (const float*)d_in[7];
    const float* Wr2 = (const float*)d_in[8];
    const float* Wl3 = (const float*)d_in[9];
    const float* bl3 = (const float*)d_in[10];
    const float* Wr3 = (const float*)d_in[11];
    const float* Wl4 = (const float*)d_in[12];
    const float* bl4 = (const float*)d_in[13];
    const float* Wr4 = (const float*)d_in[14];
    const float* Wfc = (const float*)d_in[15];
    const float* bfc = (const float*)d_in[16];
    float* out = (float*)d_out;

    // workspace layout
    _Float16* hA  = (_Float16*)d_ws;                  // [N,64] fp16
    _Float16* hB  = hA + (size_t)NN * 64;             // [N,64] fp16
    float* psum   = (float*)(hB + (size_t)NN * 64);   // [G,64]
    int*   off    = (int*)(psum + (size_t)NG * 64);   // [N+1]
    int*   bb     = off + NN + 1;                     // [NB1+1]
    int*   rowtot = bb + NB1 + 1;                     // [NB1]
    int*   rowbase = rowtot + NB1;                    // [NB1]
    int*   hist1  = rowbase + NB1;                    // [NB1*NBLK]
    int*   packed = hist1 + NB1 * NBLK;               // [E]
    int*   neigh  = packed + NE;                      // [E]

    hipMemsetAsync(psum, 0, (size_t)NG * 64 * sizeof(float), stream);

    // CSR build: atomic-free two-level bucket sort, fully parallel scan
    k_hist<<<NBLK, 256, 0, stream>>>(dst, hist1);
    k_rowsum<<<(NB1 + 3) / 4, 256, 0, stream>>>(hist1, rowtot);
    k_scanb<<<1, 1024, 0, stream>>>(rowtot, rowbase, bb);
    k_rowscan<<<(NB1 + 3) / 4, 256, 0, stream>>>(hist1, rowbase);
    k_scat<<<NBLK, 256, 0, stream>>>(src, dst, hist1, packed);
    k_bucket<<<NB1, 256, 0, stream>>>(packed, bb, neigh, off);

    // layer 1 (fused d=3 agg + transform), fp16 out
    k_l1<<<(NN + 3) / 4, 256, 0, stream>>>(off, neigh, x, Wl1, bl1, Wr1, hA);

    // layers 2-4: fused fp16 gather + dot2 transform (ping-pong hA/hB)
    const int layerGrid = (NN + 7) / 8;
    k_layer<<<layerGrid, 512, 0, stream>>>(off, neigh, (const half2v*)hA, Wl2, bl2, Wr2, hB);
    k_layer<<<layerGrid, 512, 0, stream>>>(off, neigh, (const half2v*)hB, Wl3, bl3, Wr3, hA);
    k_layer<<<layerGrid, 512, 0, stream>>>(off, neigh, (const half2v*)hA, Wl4, bl4, Wr4, hB);

    k_pool<<<NG * 8, 64, 0, stream>>>(hB, batch, psum);
    k_fc<<<NG, 128, 0, stream>>>(psum, batch, Wfc, bfc, out);
}

// Round 8
// 424.328 us; speedup vs baseline: 7.2866x; 1.0556x over previous
//
#include <hip/hip_runtime.h>

#define NN 100000
#define NE 3200000
#define NG 128
#define HID 64
#define OUTC 128

#define CHUNK 8192
#define NBLK 391                 // ceil(NE / CHUNK)
#define NB1 782                  // ceil(NN / 128) coarse buckets (dst >> 7)

typedef _Float16 half2v __attribute__((ext_vector_type(2)));
typedef _Float16 half4v __attribute__((ext_vector_type(4)));

#if __has_builtin(__builtin_amdgcn_fdot2)
#define FDOT2(a, b, c) __builtin_amdgcn_fdot2((a), (b), (c), false)
#else
#define FDOT2(a, b, c) ((c) + (float)(a).x * (float)(b).x + (float)(a).y * (float)(b).y)
#endif

// ---------------- P1: per-block coarse histogram (LDS atomics only) ----------------
__global__ __launch_bounds__(256) void k_hist(const int* __restrict__ dst,
                                              int* __restrict__ hist1) {
    __shared__ int h[NB1];
    for (int i = threadIdx.x; i < NB1; i += 256) h[i] = 0;
    __syncthreads();
    int base = blockIdx.x * CHUNK;
    int end = min(base + CHUNK, NE);
    for (int e = base + threadIdx.x; e < end; e += 256)
        atomicAdd(&h[dst[e] >> 7], 1);
    __syncthreads();
    for (int i = threadIdx.x; i < NB1; i += 256)
        hist1[i * NBLK + blockIdx.x] = h[i];
}

// ---------------- P2a: per-row totals (one wave per row) ----------------
__global__ __launch_bounds__(256) void k_rowsum(const int* __restrict__ hist1,
                                                int* __restrict__ rowtot) {
    int row = blockIdx.x * 4 + (threadIdx.x >> 6);
    int lane = threadIdx.x & 63;
    if (row >= NB1) return;
    int s = 0;
    for (int k = lane; k < NBLK; k += 64) s += hist1[row * NBLK + k];
#pragma unroll
    for (int m = 1; m < 64; m <<= 1) s += __shfl_xor(s, m);
    if (lane == 0) rowtot[row] = s;
}

// ---------------- P2b: small single-block scan of 782 row totals ----------------
__global__ __launch_bounds__(1024) void k_scanb(const int* __restrict__ rowtot,
                                                int* __restrict__ rowbase,
                                                int* __restrict__ bb) {
    __shared__ int sums[1024];
    int t = threadIdx.x;
    int v = (t < NB1) ? rowtot[t] : 0;
    sums[t] = v;
    __syncthreads();
    for (int d = 1; d < 1024; d <<= 1) {
        int u = (t >= d) ? sums[t - d] : 0;
        __syncthreads();
        sums[t] += u;
        __syncthreads();
    }
    if (t < NB1) {
        int base = sums[t] - v;   // exclusive
        rowbase[t] = base;
        bb[t] = base;
    }
    if (t == 0) bb[NB1] = NE;
}

// ---------------- P2c: per-row exclusive scan (one wave per row) ----------------
__global__ __launch_bounds__(256) void k_rowscan(int* __restrict__ hist1,
                                                 const int* __restrict__ rowbase) {
    int row = blockIdx.x * 4 + (threadIdx.x >> 6);
    int lane = threadIdx.x & 63;
    if (row >= NB1) return;
    int carry = rowbase[row];
    for (int k0 = 0; k0 < NBLK; k0 += 64) {
        int k = k0 + lane;
        int v = (k < NBLK) ? hist1[row * NBLK + k] : 0;
        int xv = v;
#pragma unroll
        for (int m = 1; m < 64; m <<= 1) {
            int y = __shfl_up(xv, m);
            if (lane >= m) xv += y;
        }
        int tot = __shfl(xv, 63);
        if (k < NBLK) hist1[row * NBLK + k] = xv - v + carry;
        carry += tot;
    }
}

// ---------------- P3: scatter into coarse buckets (LDS cursors) ----------------
__global__ __launch_bounds__(256) void k_scat(const int* __restrict__ src,
                                              const int* __restrict__ dst,
                                              const int* __restrict__ hist1,
                                              int* __restrict__ packed) {
    __shared__ int cur[NB1];
    for (int i = threadIdx.x; i < NB1; i += 256)
        cur[i] = hist1[i * NBLK + blockIdx.x];
    __syncthreads();
    int base = blockIdx.x * CHUNK;
    int end = min(base + CHUNK, NE);
    for (int e = base + threadIdx.x; e < end; e += 256) {
        int d = dst[e], s = src[e];
        int p = atomicAdd(&cur[d >> 7], 1);
        packed[p] = ((d & 127) << 17) | s;   // src < 2^17
    }
}

// ---------------- P4: within-bucket group by exact dst; emit neigh + off ----------------
__global__ __launch_bounds__(256) void k_bucket(const int* __restrict__ packed,
                                                const int* __restrict__ bb,
                                                int* __restrict__ neigh,
                                                int* __restrict__ off) {
    int b = blockIdx.x;
    int lo = bb[b], hi = bb[b + 1];
    __shared__ int cnt[128];
    __shared__ int pos[128];
    __shared__ int cur2[128];
    if (threadIdx.x < 128) cnt[threadIdx.x] = 0;
    __syncthreads();
    for (int i = lo + threadIdx.x; i < hi; i += 256)
        atomicAdd(&cnt[packed[i] >> 17], 1);
    __syncthreads();
    if (threadIdx.x == 0) {
        int run = lo;
        for (int j = 0; j < 128; ++j) { pos[j] = run; run += cnt[j]; }
    }
    __syncthreads();
    if (threadIdx.x < 128) {
        int node = b * 128 + threadIdx.x;
        if (node <= NN) off[node] = pos[threadIdx.x];
        cur2[threadIdx.x] = pos[threadIdx.x];
    }
    __syncthreads();
    for (int i = lo + threadIdx.x; i < hi; i += 256) {
        int p = packed[i];
        int j = p >> 17;
        int q = atomicAdd(&cur2[j], 1);
        neigh[q] = p & 0x1FFFF;
    }
}

// ---------------- layer 1: CSR mean-agg (d=3) + transform, fp16 out ----------------
__global__ __launch_bounds__(256) void k_l1(const int* __restrict__ off,
                                            const int* __restrict__ neigh,
                                            const float* __restrict__ x,
                                            const float* __restrict__ Wl,
                                            const float* __restrict__ bl,
                                            const float* __restrict__ Wr,
                                            _Float16* __restrict__ out) {
    int n = blockIdx.x * 4 + (threadIdx.x >> 6);
    int c = threadIdx.x & 63;
    if (n >= NN) return;
    int lo = off[n], hi = off[n + 1];
    float a0 = 0.f, a1 = 0.f, a2 = 0.f;
    for (int i = lo + c; i < hi; i += 64) {
        int s = neigh[i];
        a0 += x[s * 3 + 0];
        a1 += x[s * 3 + 1];
        a2 += x[s * 3 + 2];
    }
#pragma unroll
    for (int m = 1; m < 64; m <<= 1) {
        a0 += __shfl_xor(a0, m);
        a1 += __shfl_xor(a1, m);
        a2 += __shfl_xor(a2, m);
    }
    float ic = 1.0f / fmaxf((float)(hi - lo), 1.0f);
    a0 *= ic; a1 *= ic; a2 *= ic;
    float x0 = x[n * 3 + 0], x1 = x[n * 3 + 1], x2 = x[n * 3 + 2];
    float acc = bl[c]
              + a0 * Wl[0 * 64 + c] + a1 * Wl[1 * 64 + c] + a2 * Wl[2 * 64 + c]
              + x0 * Wr[0 * 64 + c] + x1 * Wr[1 * 64 + c] + x2 * Wr[2 * 64 + c];
    out[(size_t)n * 64 + c] = (_Float16)fmaxf(acc, 0.0f);
}

// ---------------- fused layer: fp16 quad-gather + dot2 matvec ----------------
// h: fp16 [NN][64]; out: fp16 [NN][64]. out must not alias h.
// Gather: 16-lane groups, each lane owns 4 cols (8B), 4 neighbors/iter.
__global__ __launch_bounds__(512, 8) void k_layer(const int* __restrict__ off,
                                                  const int* __restrict__ neigh,
                                                  const _Float16* __restrict__ h,
                                                  const float* __restrict__ Wl,
                                                  const float* __restrict__ bl,
                                                  const float* __restrict__ Wr,
                                                  _Float16* __restrict__ out) {
    __shared__ half2v Wpk[2][32][64];     // 16 KiB: k-pair packed Wl, Wr
    __shared__ _Float16 rowsh[2][8][64];  // mean row, root row per wave
    for (int idx = threadIdx.x; idx < 32 * 64; idx += 512) {
        int kp = idx >> 6, c = idx & 63;
        Wpk[0][kp][c] = half2v{(_Float16)Wl[(2 * kp) * 64 + c],
                               (_Float16)Wl[(2 * kp + 1) * 64 + c]};
        Wpk[1][kp][c] = half2v{(_Float16)Wr[(2 * kp) * 64 + c],
                               (_Float16)Wr[(2 * kp + 1) * 64 + c]};
    }
    __syncthreads();                      // only barrier: Wpk ready

    int li = threadIdx.x >> 6;
    int lane = threadIdx.x & 63;
    int g = lane >> 4;                    // neighbor slot within quad
    int q = lane & 15;                    // column quad (cols 4q..4q+3)
    int n = blockIdx.x * 8 + li;          // grid exact: 12500*8 = NN
    if (n >= NN) return;

    float ob = bl[lane];                  // hoisted

    int lo = __builtin_amdgcn_readfirstlane(off[n]);
    int hi = __builtin_amdgcn_readfirstlane(off[n + 1]);
    int deg = hi - lo;
    const int* __restrict__ np = neigh + lo;
    const char* __restrict__ hb = (const char*)h;
    unsigned qoff = (unsigned)q << 3;

    float ax = 0.f, ay = 0.f, az = 0.f, aw = 0.f;
    int nq = deg >> 2;
#pragma unroll 4
    for (int i = 0; i < nq; ++i) {
        int s0 = np[4 * i + 0];           // uniform -> s_load
        int s1 = np[4 * i + 1];
        int s2 = np[4 * i + 2];
        int s3 = np[4 * i + 3];
        int s = (g & 2) ? ((g & 1) ? s3 : s2) : ((g & 1) ? s1 : s0);
        unsigned o32 = ((unsigned)s << 7) | qoff;
        half4v v = *(const half4v*)(hb + o32);
        ax += (float)v.x; ay += (float)v.y; az += (float)v.z; aw += (float)v.w;
    }
    // tail (deg%4): handled by group 0 only; butterfly sums all lanes' partials
    if (g == 0) {
        for (int i = nq << 2; i < deg; ++i) {
            int s = np[i];
            unsigned o32 = ((unsigned)s << 7) | qoff;
            half4v v = *(const half4v*)(hb + o32);
            ax += (float)v.x; ay += (float)v.y; az += (float)v.z; aw += (float)v.w;
        }
    }
#pragma unroll
    for (int m = 16; m <= 32; m <<= 1) {
        ax += __shfl_xor(ax, m);
        ay += __shfl_xor(ay, m);
        az += __shfl_xor(az, m);
        aw += __shfl_xor(aw, m);
    }
    if (g == 0) {
        float ic = 1.0f / fmaxf((float)deg, 1.0f);
        half4v mv = half4v{(_Float16)(ax * ic), (_Float16)(ay * ic),
                           (_Float16)(az * ic), (_Float16)(aw * ic)};
        *(half4v*)&rowsh[0][li][4 * q] = mv;
        half4v rv = *(const half4v*)(hb + (((unsigned)n << 7) | qoff));  // root row
        *(half4v*)&rowsh[1][li][4 * q] = rv;
    }
    // same-wave ds_write -> ds_read: compiler inserts lgkmcnt wait; no barrier

    float o = ob;
#pragma unroll
    for (int k2 = 0; k2 < 32; ++k2) {
        half2v m2 = *(const half2v*)&rowsh[0][li][2 * k2];
        half2v r2 = *(const half2v*)&rowsh[1][li][2 * k2];
        o = FDOT2(m2, Wpk[0][k2][lane], o);
        o = FDOT2(r2, Wpk[1][k2][lane], o);
    }
    out[(size_t)n * 64 + lane] = (_Float16)fmaxf(o, 0.0f);
}

// ---------------- pooling helpers ----------------
__device__ __forceinline__ int lower_bound_batch(const int* __restrict__ batch, int val) {
    int lo = 0, hi = NN;
    while (lo < hi) {
        int mid = (lo + hi) >> 1;
        if (batch[mid] < val) lo = mid + 1; else hi = mid;
    }
    return lo;
}

__global__ __launch_bounds__(64) void k_pool(const _Float16* __restrict__ h,
                                             const int* __restrict__ batch,
                                             float* __restrict__ psum) {
    int g = blockIdx.x >> 3;
    int part = blockIdx.x & 7;
    int lane = threadIdx.x;
    int lo = lower_bound_batch(batch, g);
    int hi = lower_bound_batch(batch, g + 1);
    float s = 0.0f;
    for (int n = lo + part; n < hi; n += 8) s += (float)h[(size_t)n * 64 + lane];
    atomicAdd(&psum[g * 64 + lane], s);
}

__global__ __launch_bounds__(128) void k_fc(const float* __restrict__ psum,
                                            const int* __restrict__ batch,
                                            const float* __restrict__ Wfc,
                                            const float* __restrict__ bfc,
                                            float* __restrict__ out) {
    __shared__ float meanv[64];
    __shared__ float red[2];
    int g = blockIdx.x;
    int c = threadIdx.x;
    int lo = lower_bound_batch(batch, g);
    int hi = lower_bound_batch(batch, g + 1);
    float icnt = 1.0f / fmaxf((float)(hi - lo), 1.0f);
    if (c < 64) meanv[c] = psum[g * 64 + c] * icnt;
    __syncthreads();
    float acc = bfc[c];
#pragma unroll
    for (int k = 0; k < 64; ++k) acc += meanv[k] * Wfc[k * 128 + c];
    float ss = acc * acc;
#pragma unroll
    for (int off = 32; off; off >>= 1) ss += __shfl_down(ss, off);
    if ((c & 63) == 0) red[c >> 6] = ss;
    __syncthreads();
    float norm = fmaxf(sqrtf(red[0] + red[1]), 1e-12f);
    out[g * 128 + c] = acc / norm;
}

extern "C" void kernel_launch(void* const* d_in, const int* in_sizes, int n_in,
                              void* d_out, int out_size, void* d_ws, size_t ws_size,
                              hipStream_t stream) {
    const float* x    = (const float*)d_in[0];
    const int*   ei   = (const int*)d_in[1];
    const int*   src  = ei;
    const int*   dst  = ei + NE;
    const int*   batch = (const int*)d_in[2];
    const float* Wl1 = (const float*)d_in[3];
    const float* bl1 = (const float*)d_in[4];
    const float* Wr1 = (const float*)d_in[5];
    const float* Wl2 = (const float*)d_in[6];
    const float* bl2 = (const float*)d_in[7];
    const float* Wr2 = (const float*)d_in[8];
    const float* Wl3 = (const float*)d_in[9];
    const float* bl3 = (const float*)d_in[10];
    const float* Wr3 = (const float*)d_in[11];
    const float* Wl4 = (const float*)d_in[12];
    const float* bl4 = (const float*)d_in[13];
    const float* Wr4 = (const float*)d_in[14];
    const float* Wfc = (const float*)d_in[15];
    const float* bfc = (const float*)d_in[16];
    float* out = (float*)d_out;

    // workspace layout
    _Float16* hA  = (_Float16*)d_ws;                  // [N,64] fp16
    _Float16* hB  = hA + (size_t)NN * 64;             // [N,64] fp16
    float* psum   = (float*)(hB + (size_t)NN * 64);   // [G,64]
    int*   off    = (int*)(psum + (size_t)NG * 64);   // [N+1]
    int*   bb     = off + NN + 1;                     // [NB1+1]
    int*   rowtot = bb + NB1 + 1;                     // [NB1]
    int*   rowbase = rowtot + NB1;                    // [NB1]
    int*   hist1  = rowbase + NB1;                    // [NB1*NBLK]
    int*   packed = hist1 + NB1 * NBLK;               // [E]
    int*   neigh  = packed + NE;                      // [E]

    hipMemsetAsync(psum, 0, (size_t)NG * 64 * sizeof(float), stream);

    // CSR build: atomic-free two-level bucket sort, fully parallel scan
    k_hist<<<NBLK, 256, 0, stream>>>(dst, hist1);
    k_rowsum<<<(NB1 + 3) / 4, 256, 0, stream>>>(hist1, rowtot);
    k_scanb<<<1, 1024, 0, stream>>>(rowtot, rowbase, bb);
    k_rowscan<<<(NB1 + 3) / 4, 256, 0, stream>>>(hist1, rowbase);
    k_scat<<<NBLK, 256, 0, stream>>>(src, dst, hist1, packed);
    k_bucket<<<NB1, 256, 0, stream>>>(packed, bb, neigh, off);

    // layer 1 (fused d=3 agg + transform), fp16 out
    k_l1<<<(NN + 3) / 4, 256, 0, stream>>>(off, neigh, x, Wl1, bl1, Wr1, hA);

    // layers 2-4: fused fp16 quad-gather + dot2 transform (ping-pong hA/hB)
    const int layerGrid = (NN + 7) / 8;
    k_layer<<<layerGrid, 512, 0, stream>>>(off, neigh, hA, Wl2, bl2, Wr2, hB);
    k_layer<<<layerGrid, 512, 0, stream>>>(off, neigh, hB, Wl3, bl3, Wr3, hA);
    k_layer<<<layerGrid, 512, 0, stream>>>(off, neigh, hA, Wl4, bl4, Wr4, hB);

    k_pool<<<NG * 8, 64, 0, stream>>>(hB, batch, psum);
    k_fc<<<NG, 128, 0, stream>>>(psum, batch, Wfc, bfc, out);
}